// Round 1
// baseline (1899.333 us; speedup 1.0000x reference)
//
#include <hip/hip_runtime.h>

#define NN 100000
#define NE 3200000
#define NG 2000
#define FIN 14
#define HD 64
#define NC 2

// ---------------- CSR build ----------------

__global__ void k_hist(const int* __restrict__ dst, int* __restrict__ deg, int n) {
    int i = blockIdx.x * blockDim.x + threadIdx.x;
    if (i < n) atomicAdd(&deg[dst[i]], 1);
}

__global__ void k_gcnt(const int* __restrict__ batch, int* __restrict__ gcnt, int n) {
    int i = blockIdx.x * blockDim.x + threadIdx.x;
    if (i < n) atomicAdd(&gcnt[batch[i]], 1);
}

// per-block inclusive scan of deg -> incl, block sums -> bsums
__global__ void k_scan1(const int* __restrict__ deg, int* __restrict__ incl,
                        int* __restrict__ bsums, int n) {
    __shared__ int tmp[256];
    int i = blockIdx.x * 256 + threadIdx.x;
    int v = (i < n) ? deg[i] : 0;
    tmp[threadIdx.x] = v;
    __syncthreads();
    for (int off = 1; off < 256; off <<= 1) {
        int t = (threadIdx.x >= off) ? tmp[threadIdx.x - off] : 0;
        __syncthreads();
        tmp[threadIdx.x] += t;
        __syncthreads();
    }
    if (i < n) incl[i] = tmp[threadIdx.x];
    if (threadIdx.x == 255) bsums[blockIdx.x] = tmp[255];
}

// single-block exclusive scan of bsums (nb <= 512)
__global__ void k_scan2(int* bsums, int nb) {
    __shared__ int tmp[512];
    int t = threadIdx.x;
    int v = (t < nb) ? bsums[t] : 0;
    tmp[t] = v;
    __syncthreads();
    for (int off = 1; off < 512; off <<= 1) {
        int u = (t >= off) ? tmp[t - off] : 0;
        __syncthreads();
        tmp[t] += u;
        __syncthreads();
    }
    if (t < nb) bsums[t] = tmp[t] - v;  // exclusive
}

// incl -> exclusive row_start (+ cursor copy)
__global__ void k_scan3(const int* __restrict__ deg, int* __restrict__ rs,
                        int* __restrict__ cursor, const int* __restrict__ bsums, int n) {
    int i = blockIdx.x * 256 + threadIdx.x;
    if (i < n) {
        int v = rs[i] - deg[i] + bsums[blockIdx.x];
        rs[i] = v;
        cursor[i] = v;
    }
}

__global__ void k_fill(const int* __restrict__ src, const int* __restrict__ dst,
                       int* __restrict__ cursor, int* __restrict__ csr, int n) {
    int i = blockIdx.x * blockDim.x + threadIdx.x;
    if (i < n) {
        int p = atomicAdd(&cursor[dst[i]], 1);
        csr[p] = src[i];
    }
}

// ---------------- Layer 1: x[N,14] -> h[N,64], fused agg+dense+relu ----------------

__global__ __launch_bounds__(256) void k_layer1(
    const float* __restrict__ x, float* __restrict__ hout,
    const float* __restrict__ Wl, const float* __restrict__ Wr, const float* __restrict__ b,
    const int* __restrict__ rs, const int* __restrict__ deg, const int* __restrict__ csr) {
    __shared__ float sWl[FIN * HD], sWr[FIN * HD], sb[HD];
    __shared__ float sAgg[4][FIN], sX[4][FIN];
    for (int i = threadIdx.x; i < FIN * HD; i += 256) { sWl[i] = Wl[i]; sWr[i] = Wr[i]; }
    if (threadIdx.x < HD) sb[threadIdx.x] = b[threadIdx.x];
    __syncthreads();
    int lane = threadIdx.x & 63, wid = threadIdx.x >> 6;
    int ngroups = (NN + 3) / 4;
    for (int g = blockIdx.x; g < ngroups; g += gridDim.x) {
        int n = g * 4 + wid;
        bool act = n < NN;
        float acc = 0.f, xv = 0.f;
        if (act && lane < FIN) {
            int s0 = rs[n], d = deg[n];
            for (int j = 0; j < d; ++j) {
                int s = csr[s0 + j];
                acc += x[s * FIN + lane];
            }
            acc *= 1.0f / (float)(d > 1 ? d : 1);
            xv = x[n * FIN + lane];
        }
        if (lane < FIN) { sAgg[wid][lane] = acc; sX[wid][lane] = xv; }
        __syncthreads();
        float out = sb[lane];
#pragma unroll
        for (int k = 0; k < FIN; ++k)
            out += sAgg[wid][k] * sWl[k * HD + lane] + sX[wid][k] * sWr[k * HD + lane];
        out = fmaxf(out, 0.f);
        if (act) hout[n * HD + lane] = out;
        __syncthreads();
    }
}

// ---------------- H layers: h[N,64] -> h[N,64], fused agg+dense+relu (+z fusion) ----------------

template <bool FUSEZ>
__global__ __launch_bounds__(256) void k_layerH(
    const float* __restrict__ hin, float* __restrict__ hout,
    const float* __restrict__ Wl, const float* __restrict__ Wr, const float* __restrict__ b,
    const float* __restrict__ W4l, float* __restrict__ z,
    const int* __restrict__ rs, const int* __restrict__ deg, const int* __restrict__ csr) {
    __shared__ float sWl[HD * HD], sWr[HD * HD], sb[HD], sW4l[HD * NC];
    __shared__ float sAgg[4][HD], sH[4][HD];
    for (int i = threadIdx.x; i < HD * HD; i += 256) { sWl[i] = Wl[i]; sWr[i] = Wr[i]; }
    if (threadIdx.x < HD) sb[threadIdx.x] = b[threadIdx.x];
    if (FUSEZ && threadIdx.x < HD * NC) sW4l[threadIdx.x] = W4l[threadIdx.x];
    __syncthreads();
    int lane = threadIdx.x & 63, wid = threadIdx.x >> 6;
    int ngroups = (NN + 3) / 4;
    for (int g = blockIdx.x; g < ngroups; g += gridDim.x) {
        int n = g * 4 + wid;
        bool act = n < NN;
        float acc = 0.f, hv = 0.f;
        if (act) {
            int s0 = rs[n], d = deg[n];
            for (int j = 0; j < d; ++j) {
                int s = csr[s0 + j];
                acc += hin[s * HD + lane];  // 64 lanes -> coalesced 256B row
            }
            acc *= 1.0f / (float)(d > 1 ? d : 1);
            hv = hin[n * HD + lane];
        }
        sAgg[wid][lane] = acc;
        sH[wid][lane] = hv;
        __syncthreads();
        float out = sb[lane];
#pragma unroll 8
        for (int k = 0; k < HD; ++k)
            out += sAgg[wid][k] * sWl[k * HD + lane] + sH[wid][k] * sWr[k * HD + lane];
        out = fmaxf(out, 0.f);
        if (act) hout[n * HD + lane] = out;
        if (FUSEZ) {
            float r0 = out * sW4l[lane * NC + 0];
            float r1 = out * sW4l[lane * NC + 1];
            for (int off = 32; off; off >>= 1) {
                r0 += __shfl_xor(r0, off);
                r1 += __shfl_xor(r1, off);
            }
            if (act && lane == 0) {
                z[n * 2 + 0] = r0;
                z[n * 2 + 1] = r1;
            }
        }
        __syncthreads();
    }
}

// ---------------- Layer 4 + graph pooling sum ----------------

__global__ __launch_bounds__(256) void k_pool(
    const float* __restrict__ h3, const float* __restrict__ z,
    const float* __restrict__ W4r, const float* __restrict__ b4,
    const int* __restrict__ rs, const int* __restrict__ deg, const int* __restrict__ csr,
    const int* __restrict__ batch, float* __restrict__ gsum) {
    __shared__ float sW[HD * NC];
    if (threadIdx.x < HD * NC) sW[threadIdx.x] = W4r[threadIdx.x];
    __syncthreads();
    int lane = threadIdx.x & 63, wid = threadIdx.x >> 6;
    int stride = gridDim.x * 4;
    for (int n = blockIdx.x * 4 + wid; n < NN; n += stride) {
        float hv = h3[n * HD + lane];
        float r0 = hv * sW[lane * NC + 0];
        float r1 = hv * sW[lane * NC + 1];
        int s0 = rs[n], d = deg[n];
        float a0 = 0.f, a1 = 0.f;
        for (int j = lane; j < d; j += 64) {
            int s = csr[s0 + j];
            a0 += z[s * 2 + 0];
            a1 += z[s * 2 + 1];
        }
        for (int off = 32; off; off >>= 1) {
            r0 += __shfl_xor(r0, off);
            r1 += __shfl_xor(r1, off);
            a0 += __shfl_xor(a0, off);
            a1 += __shfl_xor(a1, off);
        }
        if (lane == 0) {
            float inv = 1.0f / (float)(d > 1 ? d : 1);
            float o0 = a0 * inv + r0 + b4[0];
            float o1 = a1 * inv + r1 + b4[1];
            int gg = batch[n];
            atomicAdd(&gsum[gg * 2 + 0], o0);
            atomicAdd(&gsum[gg * 2 + 1], o1);
        }
    }
}

__global__ void k_final(const float* __restrict__ gsum, const int* __restrict__ gcnt,
                        float* __restrict__ out) {
    int g = blockIdx.x * blockDim.x + threadIdx.x;
    if (g < NG) {
        float inv = 1.0f / (float)(gcnt[g] > 1 ? gcnt[g] : 1);
        float p0 = gsum[g * 2 + 0] * inv;
        float p1 = gsum[g * 2 + 1] * inv;
        float m = fmaxf(p0, p1);
        float lse = m + logf(expf(p0 - m) + expf(p1 - m));
        out[g * 2 + 0] = p0 - lse;
        out[g * 2 + 1] = p1 - lse;
    }
}

// ---------------- launch ----------------

extern "C" void kernel_launch(void* const* d_in, const int* in_sizes, int n_in,
                              void* d_out, int out_size, void* d_ws, size_t ws_size,
                              hipStream_t stream) {
    const float* x   = (const float*)d_in[0];
    const float* W1l = (const float*)d_in[1];
    const float* W1r = (const float*)d_in[2];
    const float* b1  = (const float*)d_in[3];
    const float* W2l = (const float*)d_in[4];
    const float* W2r = (const float*)d_in[5];
    const float* b2  = (const float*)d_in[6];
    const float* W3l = (const float*)d_in[7];
    const float* W3r = (const float*)d_in[8];
    const float* b3  = (const float*)d_in[9];
    const float* W4l = (const float*)d_in[10];
    const float* W4r = (const float*)d_in[11];
    const float* b4  = (const float*)d_in[12];
    const int* ei    = (const int*)d_in[13];
    const int* batch = (const int*)d_in[14];
    const int* src = ei;
    const int* dst = ei + NE;
    float* out = (float*)d_out;

    char* w = (char*)d_ws;
    int* deg    = (int*)w; w += (size_t)NN * 4;
    int* rs     = (int*)w; w += (size_t)NN * 4;
    int* cursor = (int*)w; w += (size_t)NN * 4;
    int* csr    = (int*)w; w += (size_t)NE * 4;
    int* gcnt   = (int*)w; w += (size_t)NG * 4;
    int* bsums  = (int*)w; w += 512 * 4;
    // align to 256B for the float tables
    w = (char*)(((uintptr_t)w + 255) & ~(uintptr_t)255);
    float* hA   = (float*)w; w += (size_t)NN * HD * 4;
    float* hB   = (float*)w; w += (size_t)NN * HD * 4;
    float* z    = (float*)w; w += (size_t)NN * NC * 4;
    float* gsum = (float*)w; w += (size_t)NG * NC * 4;

    const int NB = (NN + 255) / 256;   // 391 blocks over nodes
    const int EB = (NE + 255) / 256;   // edge blocks

    hipMemsetAsync(deg, 0, (size_t)NN * 4, stream);
    hipMemsetAsync(gcnt, 0, (size_t)NG * 4, stream);
    hipMemsetAsync(gsum, 0, (size_t)NG * NC * 4, stream);

    k_hist<<<EB, 256, 0, stream>>>(dst, deg, NE);
    k_gcnt<<<NB, 256, 0, stream>>>(batch, gcnt, NN);
    k_scan1<<<NB, 256, 0, stream>>>(deg, rs, bsums, NN);
    k_scan2<<<1, 512, 0, stream>>>(bsums, NB);
    k_scan3<<<NB, 256, 0, stream>>>(deg, rs, cursor, bsums, NN);
    k_fill<<<EB, 256, 0, stream>>>(src, dst, cursor, csr, NE);

    k_layer1<<<2048, 256, 0, stream>>>(x, hA, W1l, W1r, b1, rs, deg, csr);
    k_layerH<false><<<2048, 256, 0, stream>>>(hA, hB, W2l, W2r, b2, nullptr, nullptr, rs, deg, csr);
    k_layerH<true><<<2048, 256, 0, stream>>>(hB, hA, W3l, W3r, b3, W4l, z, rs, deg, csr);
    k_pool<<<2048, 256, 0, stream>>>(hA, z, W4r, b4, rs, deg, csr, batch, gsum);
    k_final<<<(NG + 255) / 256, 256, 0, stream>>>(gsum, gcnt, out);
}

// Round 2
// 976.960 us; speedup vs baseline: 1.9441x; 1.9441x over previous
//
#include <hip/hip_runtime.h>

#define NN 100000
#define NE 3200000
#define NG 2000
#define FIN 14
#define HD 64
#define NC 2

// ---------------- CSR build ----------------

__global__ void k_hist(const int* __restrict__ dst, int* __restrict__ deg, int n) {
    int i = blockIdx.x * blockDim.x + threadIdx.x;
    if (i < n) atomicAdd(&deg[dst[i]], 1);
}

__global__ void k_gcnt(const int* __restrict__ batch, int* __restrict__ gcnt, int n) {
    int i = blockIdx.x * blockDim.x + threadIdx.x;
    if (i < n) atomicAdd(&gcnt[batch[i]], 1);
}

// per-block inclusive scan of deg -> incl, block sums -> bsums
__global__ void k_scan1(const int* __restrict__ deg, int* __restrict__ incl,
                        int* __restrict__ bsums, int n) {
    __shared__ int tmp[256];
    int i = blockIdx.x * 256 + threadIdx.x;
    int v = (i < n) ? deg[i] : 0;
    tmp[threadIdx.x] = v;
    __syncthreads();
    for (int off = 1; off < 256; off <<= 1) {
        int t = (threadIdx.x >= off) ? tmp[threadIdx.x - off] : 0;
        __syncthreads();
        tmp[threadIdx.x] += t;
        __syncthreads();
    }
    if (i < n) incl[i] = tmp[threadIdx.x];
    if (threadIdx.x == 255) bsums[blockIdx.x] = tmp[255];
}

// single-block exclusive scan of bsums (nb <= 512)
__global__ void k_scan2(int* bsums, int nb) {
    __shared__ int tmp[512];
    int t = threadIdx.x;
    int v = (t < nb) ? bsums[t] : 0;
    tmp[t] = v;
    __syncthreads();
    for (int off = 1; off < 512; off <<= 1) {
        int u = (t >= off) ? tmp[t - off] : 0;
        __syncthreads();
        tmp[t] += u;
        __syncthreads();
    }
    if (t < nb) bsums[t] = tmp[t] - v;  // exclusive
}

// incl -> exclusive row_start (+ cursor copy)
__global__ void k_scan3(const int* __restrict__ deg, int* __restrict__ rs,
                        int* __restrict__ cursor, const int* __restrict__ bsums, int n) {
    int i = blockIdx.x * 256 + threadIdx.x;
    if (i < n) {
        int v = rs[i] - deg[i] + bsums[blockIdx.x];
        rs[i] = v;
        cursor[i] = v;
    }
}

__global__ void k_fill(const int* __restrict__ src, const int* __restrict__ dst,
                       int* __restrict__ cursor, int* __restrict__ csr, int n) {
    int i = blockIdx.x * blockDim.x + threadIdx.x;
    if (i < n) {
        int p = atomicAdd(&cursor[dst[i]], 1);
        csr[p] = src[i];
    }
}

// ---------------- Layer 1: x[N,14] -> h[N,64], fused agg+dense+relu ----------------

__global__ __launch_bounds__(256) void k_layer1(
    const float* __restrict__ x, float* __restrict__ hout,
    const float* __restrict__ Wl, const float* __restrict__ Wr, const float* __restrict__ b,
    const int* __restrict__ rs, const int* __restrict__ deg, const int* __restrict__ csr) {
    __shared__ float sWl[FIN * HD], sWr[FIN * HD], sb[HD];
    __shared__ float sAgg[4][FIN], sX[4][FIN];
    for (int i = threadIdx.x; i < FIN * HD; i += 256) { sWl[i] = Wl[i]; sWr[i] = Wr[i]; }
    if (threadIdx.x < HD) sb[threadIdx.x] = b[threadIdx.x];
    __syncthreads();
    int lane = threadIdx.x & 63, wid = threadIdx.x >> 6;
    int ngroups = (NN + 3) / 4;
    for (int g = blockIdx.x; g < ngroups; g += gridDim.x) {
        int n = g * 4 + wid;
        bool act = n < NN;  // wave-uniform
        float acc = 0.f, xv = 0.f;
        if (act) {
            int s0 = rs[n], d = deg[n];
            if (lane < FIN) xv = x[n * FIN + lane];
            float a0 = 0.f, a1 = 0.f, a2 = 0.f, a3 = 0.f;
            for (int base = 0; base < d; base += 64) {
                int rem = d - base; if (rem > 64) rem = 64;
                int idxv = (lane < rem) ? csr[s0 + base + lane] : 0;
                int j = 0;
                for (; j + 4 <= rem; j += 4) {
                    int i0 = __shfl(idxv, j + 0);
                    int i1 = __shfl(idxv, j + 1);
                    int i2 = __shfl(idxv, j + 2);
                    int i3 = __shfl(idxv, j + 3);
                    if (lane < FIN) {
                        a0 += x[(size_t)i0 * FIN + lane];
                        a1 += x[(size_t)i1 * FIN + lane];
                        a2 += x[(size_t)i2 * FIN + lane];
                        a3 += x[(size_t)i3 * FIN + lane];
                    }
                }
                for (; j < rem; ++j) {
                    int i0 = __shfl(idxv, j);
                    if (lane < FIN) a0 += x[(size_t)i0 * FIN + lane];
                }
            }
            acc = ((a0 + a1) + (a2 + a3)) * (1.0f / (float)(d > 1 ? d : 1));
        }
        if (lane < FIN) { sAgg[wid][lane] = acc; sX[wid][lane] = xv; }
        __syncthreads();
        float out = sb[lane];
#pragma unroll
        for (int k = 0; k < FIN; ++k)
            out += sAgg[wid][k] * sWl[k * HD + lane] + sX[wid][k] * sWr[k * HD + lane];
        out = fmaxf(out, 0.f);
        if (act) hout[(size_t)n * HD + lane] = out;
        __syncthreads();
    }
}

// ---------------- H layers: h[N,64] -> h[N,64], fused agg+dense+relu (+z fusion) ----------------

template <bool FUSEZ>
__global__ __launch_bounds__(256) void k_layerH(
    const float* __restrict__ hin, float* __restrict__ hout,
    const float* __restrict__ Wl, const float* __restrict__ Wr, const float* __restrict__ b,
    const float* __restrict__ W4l, float* __restrict__ z,
    const int* __restrict__ rs, const int* __restrict__ deg, const int* __restrict__ csr) {
    __shared__ float sWl[HD * HD], sWr[HD * HD], sb[HD], sW4l[HD * NC];
    __shared__ float sAgg[4][HD], sH[4][HD];
    for (int i = threadIdx.x; i < HD * HD; i += 256) { sWl[i] = Wl[i]; sWr[i] = Wr[i]; }
    if (threadIdx.x < HD) sb[threadIdx.x] = b[threadIdx.x];
    if (FUSEZ && threadIdx.x < HD * NC) sW4l[threadIdx.x] = W4l[threadIdx.x];
    __syncthreads();
    int lane = threadIdx.x & 63, wid = threadIdx.x >> 6;
    int ngroups = (NN + 3) / 4;
    for (int g = blockIdx.x; g < ngroups; g += gridDim.x) {
        int n = g * 4 + wid;
        bool act = n < NN;  // wave-uniform
        float acc = 0.f, hv = 0.f;
        if (act) {
            int s0 = rs[n], d = deg[n];
            hv = hin[(size_t)n * HD + lane];
            float a0 = 0.f, a1 = 0.f, a2 = 0.f, a3 = 0.f;
            float a4 = 0.f, a5 = 0.f, a6 = 0.f, a7 = 0.f;
            for (int base = 0; base < d; base += 64) {
                int rem = d - base; if (rem > 64) rem = 64;
                int idxv = (lane < rem) ? csr[s0 + base + lane] : 0;
                int j = 0;
                for (; j + 8 <= rem; j += 8) {
                    int i0 = __shfl(idxv, j + 0);
                    int i1 = __shfl(idxv, j + 1);
                    int i2 = __shfl(idxv, j + 2);
                    int i3 = __shfl(idxv, j + 3);
                    int i4 = __shfl(idxv, j + 4);
                    int i5 = __shfl(idxv, j + 5);
                    int i6 = __shfl(idxv, j + 6);
                    int i7 = __shfl(idxv, j + 7);
                    a0 += hin[(size_t)i0 * HD + lane];
                    a1 += hin[(size_t)i1 * HD + lane];
                    a2 += hin[(size_t)i2 * HD + lane];
                    a3 += hin[(size_t)i3 * HD + lane];
                    a4 += hin[(size_t)i4 * HD + lane];
                    a5 += hin[(size_t)i5 * HD + lane];
                    a6 += hin[(size_t)i6 * HD + lane];
                    a7 += hin[(size_t)i7 * HD + lane];
                }
                for (; j < rem; ++j) {
                    int i0 = __shfl(idxv, j);
                    a0 += hin[(size_t)i0 * HD + lane];
                }
            }
            acc = (((a0 + a1) + (a2 + a3)) + ((a4 + a5) + (a6 + a7)))
                  * (1.0f / (float)(d > 1 ? d : 1));
        }
        sAgg[wid][lane] = acc;
        sH[wid][lane] = hv;
        __syncthreads();
        float out = sb[lane];
#pragma unroll 8
        for (int k = 0; k < HD; ++k)
            out += sAgg[wid][k] * sWl[k * HD + lane] + sH[wid][k] * sWr[k * HD + lane];
        out = fmaxf(out, 0.f);
        if (act) hout[(size_t)n * HD + lane] = out;
        if (FUSEZ) {
            float r0 = out * sW4l[lane * NC + 0];
            float r1 = out * sW4l[lane * NC + 1];
            for (int off = 32; off; off >>= 1) {
                r0 += __shfl_xor(r0, off);
                r1 += __shfl_xor(r1, off);
            }
            if (act && lane == 0) {
                float2* z2 = (float2*)z;
                z2[n] = make_float2(r0, r1);
            }
        }
        __syncthreads();
    }
}

// ---------------- Layer 4 + graph pooling sum ----------------

__global__ __launch_bounds__(256) void k_pool(
    const float* __restrict__ h3, const float* __restrict__ z,
    const float* __restrict__ W4r, const float* __restrict__ b4,
    const int* __restrict__ rs, const int* __restrict__ deg, const int* __restrict__ csr,
    const int* __restrict__ batch, float* __restrict__ gsum) {
    __shared__ float sW[HD * NC];
    if (threadIdx.x < HD * NC) sW[threadIdx.x] = W4r[threadIdx.x];
    __syncthreads();
    const float2* z2 = (const float2*)z;
    int lane = threadIdx.x & 63, wid = threadIdx.x >> 6;
    int stride = gridDim.x * 4;
    for (int n = blockIdx.x * 4 + wid; n < NN; n += stride) {
        float hv = h3[(size_t)n * HD + lane];
        float r0 = hv * sW[lane * NC + 0];
        float r1 = hv * sW[lane * NC + 1];
        int s0 = rs[n], d = deg[n];
        float a0 = 0.f, a1 = 0.f;
        for (int j = lane; j < d; j += 64) {
            int s = csr[s0 + j];
            float2 zv = z2[s];
            a0 += zv.x;
            a1 += zv.y;
        }
        for (int off = 32; off; off >>= 1) {
            r0 += __shfl_xor(r0, off);
            r1 += __shfl_xor(r1, off);
            a0 += __shfl_xor(a0, off);
            a1 += __shfl_xor(a1, off);
        }
        if (lane == 0) {
            float inv = 1.0f / (float)(d > 1 ? d : 1);
            float o0 = a0 * inv + r0 + b4[0];
            float o1 = a1 * inv + r1 + b4[1];
            int gg = batch[n];
            atomicAdd(&gsum[gg * 2 + 0], o0);
            atomicAdd(&gsum[gg * 2 + 1], o1);
        }
    }
}

__global__ void k_final(const float* __restrict__ gsum, const int* __restrict__ gcnt,
                        float* __restrict__ out) {
    int g = blockIdx.x * blockDim.x + threadIdx.x;
    if (g < NG) {
        float inv = 1.0f / (float)(gcnt[g] > 1 ? gcnt[g] : 1);
        float p0 = gsum[g * 2 + 0] * inv;
        float p1 = gsum[g * 2 + 1] * inv;
        float m = fmaxf(p0, p1);
        float lse = m + logf(expf(p0 - m) + expf(p1 - m));
        out[g * 2 + 0] = p0 - lse;
        out[g * 2 + 1] = p1 - lse;
    }
}

// ---------------- launch ----------------

extern "C" void kernel_launch(void* const* d_in, const int* in_sizes, int n_in,
                              void* d_out, int out_size, void* d_ws, size_t ws_size,
                              hipStream_t stream) {
    const float* x   = (const float*)d_in[0];
    const float* W1l = (const float*)d_in[1];
    const float* W1r = (const float*)d_in[2];
    const float* b1  = (const float*)d_in[3];
    const float* W2l = (const float*)d_in[4];
    const float* W2r = (const float*)d_in[5];
    const float* b2  = (const float*)d_in[6];
    const float* W3l = (const float*)d_in[7];
    const float* W3r = (const float*)d_in[8];
    const float* b3  = (const float*)d_in[9];
    const float* W4l = (const float*)d_in[10];
    const float* W4r = (const float*)d_in[11];
    const float* b4  = (const float*)d_in[12];
    const int* ei    = (const int*)d_in[13];
    const int* batch = (const int*)d_in[14];
    const int* src = ei;
    const int* dst = ei + NE;
    float* out = (float*)d_out;

    char* w = (char*)d_ws;
    int* deg    = (int*)w; w += (size_t)NN * 4;
    int* rs     = (int*)w; w += (size_t)NN * 4;
    int* cursor = (int*)w; w += (size_t)NN * 4;
    int* csr    = (int*)w; w += (size_t)NE * 4;
    int* gcnt   = (int*)w; w += (size_t)NG * 4;
    int* bsums  = (int*)w; w += 512 * 4;
    // align to 256B for the float tables
    w = (char*)(((uintptr_t)w + 255) & ~(uintptr_t)255);
    float* hA   = (float*)w; w += (size_t)NN * HD * 4;
    float* hB   = (float*)w; w += (size_t)NN * HD * 4;
    float* z    = (float*)w; w += (size_t)NN * NC * 4;
    float* gsum = (float*)w; w += (size_t)NG * NC * 4;

    const int NB = (NN + 255) / 256;   // 391 blocks over nodes
    const int EB = (NE + 255) / 256;   // edge blocks

    hipMemsetAsync(deg, 0, (size_t)NN * 4, stream);
    hipMemsetAsync(gcnt, 0, (size_t)NG * 4, stream);
    hipMemsetAsync(gsum, 0, (size_t)NG * NC * 4, stream);

    k_hist<<<EB, 256, 0, stream>>>(dst, deg, NE);
    k_gcnt<<<NB, 256, 0, stream>>>(batch, gcnt, NN);
    k_scan1<<<NB, 256, 0, stream>>>(deg, rs, bsums, NN);
    k_scan2<<<1, 512, 0, stream>>>(bsums, NB);
    k_scan3<<<NB, 256, 0, stream>>>(deg, rs, cursor, bsums, NN);
    k_fill<<<EB, 256, 0, stream>>>(src, dst, cursor, csr, NE);

    k_layer1<<<2048, 256, 0, stream>>>(x, hA, W1l, W1r, b1, rs, deg, csr);
    k_layerH<false><<<2048, 256, 0, stream>>>(hA, hB, W2l, W2r, b2, nullptr, nullptr, rs, deg, csr);
    k_layerH<true><<<2048, 256, 0, stream>>>(hB, hA, W3l, W3r, b3, W4l, z, rs, deg, csr);
    k_pool<<<2048, 256, 0, stream>>>(hA, z, W4r, b4, rs, deg, csr, batch, gsum);
    k_final<<<(NG + 255) / 256, 256, 0, stream>>>(gsum, gcnt, out);
}

// Round 3
// 706.352 us; speedup vs baseline: 2.6889x; 1.3831x over previous
//
#include <hip/hip_runtime.h>

#define NN 100000
#define NE 3200000
#define NG 2000
#define FIN 14
#define HD 64
#define NC 2

#define NBUK 256
#define BNODES 391      // 256*391 = 100096 >= NN
#define P1E 4096        // edges per pass-1 block
#define BUFCAP 13312    // pass-2 LDS csr slice capacity (mean 12509, +7 sigma)

// ---------------- CSR build ----------------

__global__ void k_hist(const int* __restrict__ dst, int* __restrict__ deg,
                       const int* __restrict__ batch, int* __restrict__ gcnt) {
    int i = blockIdx.x * blockDim.x + threadIdx.x;
    if (i < NE) atomicAdd(&deg[dst[i]], 1);
    if (i < NN) atomicAdd(&gcnt[batch[i]], 1);
}

// per-block inclusive scan of deg -> incl, block sums -> bsums
__global__ void k_scan1(const int* __restrict__ deg, int* __restrict__ incl,
                        int* __restrict__ bsums, int n) {
    __shared__ int tmp[256];
    int i = blockIdx.x * 256 + threadIdx.x;
    int v = (i < n) ? deg[i] : 0;
    tmp[threadIdx.x] = v;
    __syncthreads();
    for (int off = 1; off < 256; off <<= 1) {
        int t = (threadIdx.x >= off) ? tmp[threadIdx.x - off] : 0;
        __syncthreads();
        tmp[threadIdx.x] += t;
        __syncthreads();
    }
    if (i < n) incl[i] = tmp[threadIdx.x];
    if (threadIdx.x == 255) bsums[blockIdx.x] = tmp[255];
}

// single-block exclusive scan of bsums (nb <= 512)
__global__ void k_scan2(int* bsums, int nb) {
    __shared__ int tmp[512];
    int t = threadIdx.x;
    int v = (t < nb) ? bsums[t] : 0;
    tmp[t] = v;
    __syncthreads();
    for (int off = 1; off < 512; off <<= 1) {
        int u = (t >= off) ? tmp[t - off] : 0;
        __syncthreads();
        tmp[t] += u;
        __syncthreads();
    }
    if (t < nb) bsums[t] = tmp[t] - v;  // exclusive
}

// incl -> exclusive row_start (+ global cursor copy for fallback)
__global__ void k_scan3(const int* __restrict__ deg, int* __restrict__ rs,
                        int* __restrict__ cursor, const int* __restrict__ bsums, int n) {
    int i = blockIdx.x * 256 + threadIdx.x;
    if (i < n) {
        int v = rs[i] - deg[i] + bsums[blockIdx.x];
        rs[i] = v;
        cursor[i] = v;
    }
}

__global__ void k_binit(const int* __restrict__ rs, int* __restrict__ bcur) {
    int b = threadIdx.x;
    if (b < NBUK) {
        int n0 = b * BNODES;
        bcur[b] = (n0 < NN) ? rs[n0] : NE;
    }
}

// pass 1: block-local binning by dst-bucket, coalesced run writes of (src,dst)
__global__ __launch_bounds__(256) void k_pass1(
    const int* __restrict__ src, const int* __restrict__ dst,
    int* __restrict__ bcur, int2* __restrict__ pairs) {
    __shared__ int cnt[NBUK];
    __shared__ int scanb[NBUK + 1];
    __shared__ int cur[NBUK];
    __shared__ int gbase[NBUK];
    __shared__ int2 pbuf[P1E];
    __shared__ unsigned char bsl[P1E];
    int t = threadIdx.x;
    int e0 = blockIdx.x * P1E;
    int m = NE - e0; if (m > P1E) m = P1E;
    cnt[t] = 0;
    __syncthreads();
    int ds[16], ss[16], bk[16];
#pragma unroll
    for (int j = 0; j < 16; ++j) {
        int e = t + j * 256;
        if (e < m) {
            ds[j] = dst[e0 + e];
            ss[j] = src[e0 + e];
            bk[j] = ds[j] / BNODES;
            atomicAdd(&cnt[bk[j]], 1);
        } else bk[j] = -1;
    }
    __syncthreads();
    int v = cnt[t];
    scanb[t] = v;
    __syncthreads();
    for (int off = 1; off < 256; off <<= 1) {
        int u = (t >= off) ? scanb[t - off] : 0;
        __syncthreads();
        scanb[t] += u;
        __syncthreads();
    }
    int excl = scanb[t] - v;      // own slot only
    scanb[t] = excl;
    cur[t] = excl;
    if (t == 255) scanb[256] = excl + v;  // == m
    __syncthreads();
#pragma unroll
    for (int j = 0; j < 16; ++j) {
        if (bk[j] >= 0) {
            int p = atomicAdd(&cur[bk[j]], 1);
            pbuf[p] = make_int2(ss[j], ds[j]);
            bsl[p] = (unsigned char)bk[j];
        }
    }
    int cb = scanb[t + 1] - scanb[t];
    if (cb > 0) gbase[t] = atomicAdd(&bcur[t], cb);
    __syncthreads();
    for (int s = t; s < m; s += 256) {
        int b = bsl[s];
        pairs[gbase[b] + (s - scanb[b])] = pbuf[s];
    }
}

// pass 2: one block per bucket; build csr slice in LDS, stream out coalesced
__global__ __launch_bounds__(256) void k_pass2(
    const int2* __restrict__ pairs, const int* __restrict__ rs,
    int* __restrict__ gcur, int* __restrict__ csr) {
    __shared__ int buf[BUFCAP];
    __shared__ int c[BNODES];
    int b = blockIdx.x;
    int n0 = b * BNODES;
    if (n0 >= NN) return;
    int n1 = n0 + BNODES; if (n1 > NN) n1 = NN;
    int t = threadIdx.x;
    int base = rs[n0];
    int end = (n1 >= NN) ? NE : rs[n1];
    int m = end - base;
    if (m <= BUFCAP) {
        for (int i = n0 + t; i < n1; i += 256) c[i - n0] = rs[i] - base;
        __syncthreads();
        for (int s = t; s < m; s += 256) {
            int2 pr = pairs[base + s];
            int p = atomicAdd(&c[pr.y - n0], 1);
            buf[p] = pr.x;
        }
        __syncthreads();
        for (int s = t; s < m; s += 256) csr[base + s] = buf[s];
    } else {
        for (int s = t; s < m; s += 256) {
            int2 pr = pairs[base + s];
            int p = atomicAdd(&gcur[pr.y], 1);
            csr[p] = pr.x;
        }
    }
}

// ---------------- Layer 1: x[N,14] -> h[N,64], fused agg+dense+relu ----------------

__global__ __launch_bounds__(256) void k_layer1(
    const float* __restrict__ x, float* __restrict__ hout,
    const float* __restrict__ Wl, const float* __restrict__ Wr, const float* __restrict__ b,
    const int* __restrict__ rs, const int* __restrict__ deg, const int* __restrict__ csr) {
    __shared__ float sWl[FIN * HD], sWr[FIN * HD], sb[HD];
    __shared__ float sAgg[4][FIN], sX[4][FIN];
    for (int i = threadIdx.x; i < FIN * HD; i += 256) { sWl[i] = Wl[i]; sWr[i] = Wr[i]; }
    if (threadIdx.x < HD) sb[threadIdx.x] = b[threadIdx.x];
    __syncthreads();
    int lane = threadIdx.x & 63, wid = threadIdx.x >> 6;
    int ngroups = (NN + 3) / 4;
    for (int g = blockIdx.x; g < ngroups; g += gridDim.x) {
        int n = g * 4 + wid;
        bool act = n < NN;
        float acc = 0.f, xv = 0.f;
        if (act) {
            int s0 = rs[n], d = deg[n];
            if (lane < FIN) xv = x[n * FIN + lane];
            float a0 = 0.f, a1 = 0.f, a2 = 0.f, a3 = 0.f;
            for (int base = 0; base < d; base += 64) {
                int rem = d - base; if (rem > 64) rem = 64;
                int idxv = (lane < rem) ? csr[s0 + base + lane] : 0;
                int j = 0;
                for (; j + 4 <= rem; j += 4) {
                    int i0 = __shfl(idxv, j + 0);
                    int i1 = __shfl(idxv, j + 1);
                    int i2 = __shfl(idxv, j + 2);
                    int i3 = __shfl(idxv, j + 3);
                    if (lane < FIN) {
                        a0 += x[(size_t)i0 * FIN + lane];
                        a1 += x[(size_t)i1 * FIN + lane];
                        a2 += x[(size_t)i2 * FIN + lane];
                        a3 += x[(size_t)i3 * FIN + lane];
                    }
                }
                for (; j < rem; ++j) {
                    int i0 = __shfl(idxv, j);
                    if (lane < FIN) a0 += x[(size_t)i0 * FIN + lane];
                }
            }
            acc = ((a0 + a1) + (a2 + a3)) * (1.0f / (float)(d > 1 ? d : 1));
        }
        if (lane < FIN) { sAgg[wid][lane] = acc; sX[wid][lane] = xv; }
        __syncthreads();
        float out = sb[lane];
#pragma unroll
        for (int k = 0; k < FIN; ++k)
            out += sAgg[wid][k] * sWl[k * HD + lane] + sX[wid][k] * sWr[k * HD + lane];
        out = fmaxf(out, 0.f);
        if (act) hout[(size_t)n * HD + lane] = out;
        __syncthreads();
    }
}

// ---------------- H layers: float4-wide gather, 4 edges per instruction ----------------

__device__ __forceinline__ void f4add(float4& a, const float4 v) {
    a.x += v.x; a.y += v.y; a.z += v.z; a.w += v.w;
}

template <bool FUSEZ>
__global__ __launch_bounds__(256) void k_layerH(
    const float* __restrict__ hin, float* __restrict__ hout,
    const float* __restrict__ Wl, const float* __restrict__ Wr, const float* __restrict__ b,
    const float* __restrict__ W4l, float* __restrict__ z,
    const int* __restrict__ rs, const int* __restrict__ deg, const int* __restrict__ csr) {
    __shared__ float sWl[HD * HD], sWr[HD * HD], sb[HD], sW4l[HD * NC];
    __shared__ float sAgg[4][HD], sH[4][HD];
    for (int i = threadIdx.x; i < HD * HD; i += 256) { sWl[i] = Wl[i]; sWr[i] = Wr[i]; }
    if (threadIdx.x < HD) sb[threadIdx.x] = b[threadIdx.x];
    if (FUSEZ && threadIdx.x < HD * NC) sW4l[threadIdx.x] = W4l[threadIdx.x];
    __syncthreads();
    const float4* hin4 = (const float4*)hin;
    int lane = threadIdx.x & 63, wid = threadIdx.x >> 6;
    int sub = lane >> 4;        // edge sub-slot 0..3
    int fq = lane & 15;         // float4 index within row
    int ngroups = (NN + 3) / 4;
    for (int g = blockIdx.x; g < ngroups; g += gridDim.x) {
        int n = g * 4 + wid;
        bool act = n < NN;  // wave-uniform
        float4 S = make_float4(0.f, 0.f, 0.f, 0.f);
        float hv = 0.f;
        if (act) {
            int s0 = rs[n], d = deg[n];
            hv = hin[(size_t)n * HD + lane];
            float4 A0 = S, A1 = S, A2 = S, A3 = S, A4 = S, A5 = S, A6 = S, A7 = S;
            for (int base = 0; base < d; base += 64) {
                int rem = d - base; if (rem > 64) rem = 64;
                int idxv = (lane < rem) ? csr[s0 + base + lane] : 0;
                int j = 0;
                for (; j + 32 <= rem; j += 32) {
                    int i0 = __shfl(idxv, j + 0 + sub);
                    int i1 = __shfl(idxv, j + 4 + sub);
                    int i2 = __shfl(idxv, j + 8 + sub);
                    int i3 = __shfl(idxv, j + 12 + sub);
                    int i4 = __shfl(idxv, j + 16 + sub);
                    int i5 = __shfl(idxv, j + 20 + sub);
                    int i6 = __shfl(idxv, j + 24 + sub);
                    int i7 = __shfl(idxv, j + 28 + sub);
                    f4add(A0, hin4[(size_t)i0 * 16 + fq]);
                    f4add(A1, hin4[(size_t)i1 * 16 + fq]);
                    f4add(A2, hin4[(size_t)i2 * 16 + fq]);
                    f4add(A3, hin4[(size_t)i3 * 16 + fq]);
                    f4add(A4, hin4[(size_t)i4 * 16 + fq]);
                    f4add(A5, hin4[(size_t)i5 * 16 + fq]);
                    f4add(A6, hin4[(size_t)i6 * 16 + fq]);
                    f4add(A7, hin4[(size_t)i7 * 16 + fq]);
                }
                for (; j + 4 <= rem; j += 4) {
                    int i0 = __shfl(idxv, j + sub);
                    f4add(A0, hin4[(size_t)i0 * 16 + fq]);
                }
                if (j < rem) {
                    int i0 = __shfl(idxv, j + sub);
                    if (sub < rem - j) f4add(A0, hin4[(size_t)i0 * 16 + fq]);
                }
            }
            f4add(A0, A1); f4add(A2, A3); f4add(A4, A5); f4add(A6, A7);
            f4add(A0, A2); f4add(A4, A6); f4add(A0, A4);
            S = A0;
            // combine the 4 edge sub-slots
            for (int off = 16; off <= 32; off <<= 1) {
                S.x += __shfl_xor(S.x, off);
                S.y += __shfl_xor(S.y, off);
                S.z += __shfl_xor(S.z, off);
                S.w += __shfl_xor(S.w, off);
            }
            float inv = 1.0f / (float)(d > 1 ? d : 1);
            S.x *= inv; S.y *= inv; S.z *= inv; S.w *= inv;
        }
        if (lane < 16) ((float4*)sAgg[wid])[fq] = S;
        sH[wid][lane] = hv;
        __syncthreads();
        float out = sb[lane];
#pragma unroll 8
        for (int k = 0; k < HD; ++k)
            out += sAgg[wid][k] * sWl[k * HD + lane] + sH[wid][k] * sWr[k * HD + lane];
        out = fmaxf(out, 0.f);
        if (act) hout[(size_t)n * HD + lane] = out;
        if (FUSEZ) {
            float r0 = out * sW4l[lane * NC + 0];
            float r1 = out * sW4l[lane * NC + 1];
            for (int off = 32; off; off >>= 1) {
                r0 += __shfl_xor(r0, off);
                r1 += __shfl_xor(r1, off);
            }
            if (act && lane == 0) {
                float2* z2 = (float2*)z;
                z2[n] = make_float2(r0, r1);
            }
        }
        __syncthreads();
    }
}

// ---------------- Layer 4 + graph pooling sum ----------------

__global__ __launch_bounds__(256) void k_pool(
    const float* __restrict__ h3, const float* __restrict__ z,
    const float* __restrict__ W4r, const float* __restrict__ b4,
    const int* __restrict__ rs, const int* __restrict__ deg, const int* __restrict__ csr,
    const int* __restrict__ batch, float* __restrict__ gsum) {
    __shared__ float sW[HD * NC];
    if (threadIdx.x < HD * NC) sW[threadIdx.x] = W4r[threadIdx.x];
    __syncthreads();
    const float2* z2 = (const float2*)z;
    int lane = threadIdx.x & 63, wid = threadIdx.x >> 6;
    int stride = gridDim.x * 4;
    for (int n = blockIdx.x * 4 + wid; n < NN; n += stride) {
        float hv = h3[(size_t)n * HD + lane];
        float r0 = hv * sW[lane * NC + 0];
        float r1 = hv * sW[lane * NC + 1];
        int s0 = rs[n], d = deg[n];
        float a0 = 0.f, a1 = 0.f;
        for (int j = lane; j < d; j += 64) {
            int s = csr[s0 + j];
            float2 zv = z2[s];
            a0 += zv.x;
            a1 += zv.y;
        }
        for (int off = 32; off; off >>= 1) {
            r0 += __shfl_xor(r0, off);
            r1 += __shfl_xor(r1, off);
            a0 += __shfl_xor(a0, off);
            a1 += __shfl_xor(a1, off);
        }
        if (lane == 0) {
            float inv = 1.0f / (float)(d > 1 ? d : 1);
            float o0 = a0 * inv + r0 + b4[0];
            float o1 = a1 * inv + r1 + b4[1];
            int gg = batch[n];
            atomicAdd(&gsum[gg * 2 + 0], o0);
            atomicAdd(&gsum[gg * 2 + 1], o1);
        }
    }
}

__global__ void k_final(const float* __restrict__ gsum, const int* __restrict__ gcnt,
                        float* __restrict__ out) {
    int g = blockIdx.x * blockDim.x + threadIdx.x;
    if (g < NG) {
        float inv = 1.0f / (float)(gcnt[g] > 1 ? gcnt[g] : 1);
        float p0 = gsum[g * 2 + 0] * inv;
        float p1 = gsum[g * 2 + 1] * inv;
        float m = fmaxf(p0, p1);
        float lse = m + logf(expf(p0 - m) + expf(p1 - m));
        out[g * 2 + 0] = p0 - lse;
        out[g * 2 + 1] = p1 - lse;
    }
}

// ---------------- launch ----------------

extern "C" void kernel_launch(void* const* d_in, const int* in_sizes, int n_in,
                              void* d_out, int out_size, void* d_ws, size_t ws_size,
                              hipStream_t stream) {
    const float* x   = (const float*)d_in[0];
    const float* W1l = (const float*)d_in[1];
    const float* W1r = (const float*)d_in[2];
    const float* b1  = (const float*)d_in[3];
    const float* W2l = (const float*)d_in[4];
    const float* W2r = (const float*)d_in[5];
    const float* b2  = (const float*)d_in[6];
    const float* W3l = (const float*)d_in[7];
    const float* W3r = (const float*)d_in[8];
    const float* b3  = (const float*)d_in[9];
    const float* W4l = (const float*)d_in[10];
    const float* W4r = (const float*)d_in[11];
    const float* b4  = (const float*)d_in[12];
    const int* ei    = (const int*)d_in[13];
    const int* batch = (const int*)d_in[14];
    const int* src = ei;
    const int* dst = ei + NE;
    float* out = (float*)d_out;

    char* w = (char*)d_ws;
    int* deg    = (int*)w; w += (size_t)NN * 4;
    int* rs     = (int*)w; w += (size_t)NN * 4;
    int* cursor = (int*)w; w += (size_t)NN * 4;
    int* csr    = (int*)w; w += (size_t)NE * 4;
    int* gcnt   = (int*)w; w += (size_t)NG * 4;
    int* bsums  = (int*)w; w += 512 * 4;
    int* bcur   = (int*)w; w += NBUK * 4;
    // align to 256B for the float tables
    w = (char*)(((uintptr_t)w + 255) & ~(uintptr_t)255);
    float* hA   = (float*)w; w += (size_t)NN * HD * 4;
    float* hB   = (float*)w; w += (size_t)NN * HD * 4;
    float* z    = (float*)w; w += (size_t)NN * NC * 4;
    float* gsum = (float*)w; w += (size_t)NG * NC * 4;
    int2* pairs = (int2*)hB;   // alias: NE*8 == NN*HD*4 bytes; dead before layer 2

    const int NB = (NN + 255) / 256;   // 391
    const int EB = (NE + 255) / 256;
    const int P1B = (NE + P1E - 1) / P1E;  // 782

    hipMemsetAsync(deg, 0, (size_t)NN * 4, stream);
    hipMemsetAsync(gcnt, 0, (size_t)NG * 4, stream);
    hipMemsetAsync(gsum, 0, (size_t)NG * NC * 4, stream);

    k_hist<<<EB, 256, 0, stream>>>(dst, deg, batch, gcnt);
    k_scan1<<<NB, 256, 0, stream>>>(deg, rs, bsums, NN);
    k_scan2<<<1, 512, 0, stream>>>(bsums, NB);
    k_scan3<<<NB, 256, 0, stream>>>(deg, rs, cursor, bsums, NN);
    k_binit<<<1, 256, 0, stream>>>(rs, bcur);
    k_pass1<<<P1B, 256, 0, stream>>>(src, dst, bcur, pairs);
    k_pass2<<<NBUK, 256, 0, stream>>>(pairs, rs, cursor, csr);

    k_layer1<<<2048, 256, 0, stream>>>(x, hA, W1l, W1r, b1, rs, deg, csr);
    k_layerH<false><<<2048, 256, 0, stream>>>(hA, hB, W2l, W2r, b2, nullptr, nullptr, rs, deg, csr);
    k_layerH<true><<<2048, 256, 0, stream>>>(hB, hA, W3l, W3r, b3, W4l, z, rs, deg, csr);
    k_pool<<<2048, 256, 0, stream>>>(hA, z, W4r, b4, rs, deg, csr, batch, gsum);
    k_final<<<(NG + 255) / 256, 256, 0, stream>>>(gsum, gcnt, out);
}

// Round 4
// 703.128 us; speedup vs baseline: 2.7013x; 1.0046x over previous
//
#include <hip/hip_runtime.h>

#define NN 100000
#define NE 3200000
#define NG 2000
#define FIN 14
#define HD 64
#define NC 2

#define NBUK 256
#define BNODES 391      // 256*391 = 100096 >= NN
#define P1E 4096        // edges per pass-1 block
#define BUFCAP 13312    // pass-2 LDS csr slice capacity

typedef unsigned int uint;

__device__ __forceinline__ uint pack2bf16(float a, float b) {
    uint ua = __float_as_uint(a), ub = __float_as_uint(b);
    ua = (ua + 0x7FFFu + ((ua >> 16) & 1u)) >> 16;
    ub = (ub + 0x7FFFu + ((ub >> 16) & 1u)) >> 16;
    return ua | (ub << 16);
}
__device__ __forceinline__ float bflo(uint u) { return __uint_as_float(u << 16); }
__device__ __forceinline__ float bfhi(uint u) { return __uint_as_float(u & 0xFFFF0000u); }

// ---------------- CSR build ----------------

__global__ void k_hist(const int* __restrict__ dst, int* __restrict__ deg,
                       const int* __restrict__ batch, int* __restrict__ gcnt) {
    int i = blockIdx.x * blockDim.x + threadIdx.x;
    if (i < NE) atomicAdd(&deg[dst[i]], 1);
    if (i < NN) atomicAdd(&gcnt[batch[i]], 1);
}

__global__ void k_scan1(const int* __restrict__ deg, int* __restrict__ incl,
                        int* __restrict__ bsums, int n) {
    __shared__ int tmp[256];
    int i = blockIdx.x * 256 + threadIdx.x;
    int v = (i < n) ? deg[i] : 0;
    tmp[threadIdx.x] = v;
    __syncthreads();
    for (int off = 1; off < 256; off <<= 1) {
        int t = (threadIdx.x >= off) ? tmp[threadIdx.x - off] : 0;
        __syncthreads();
        tmp[threadIdx.x] += t;
        __syncthreads();
    }
    if (i < n) incl[i] = tmp[threadIdx.x];
    if (threadIdx.x == 255) bsums[blockIdx.x] = tmp[255];
}

__global__ void k_scan2(int* bsums, int nb) {
    __shared__ int tmp[512];
    int t = threadIdx.x;
    int v = (t < nb) ? bsums[t] : 0;
    tmp[t] = v;
    __syncthreads();
    for (int off = 1; off < 512; off <<= 1) {
        int u = (t >= off) ? tmp[t - off] : 0;
        __syncthreads();
        tmp[t] += u;
        __syncthreads();
    }
    if (t < nb) bsums[t] = tmp[t] - v;  // exclusive
}

__global__ void k_scan3(const int* __restrict__ deg, int* __restrict__ rs,
                        int* __restrict__ cursor, const int* __restrict__ bsums, int n) {
    int i = blockIdx.x * 256 + threadIdx.x;
    if (i < n) {
        int v = rs[i] - deg[i] + bsums[blockIdx.x];
        rs[i] = v;
        cursor[i] = v;
    }
}

__global__ void k_binit(const int* __restrict__ rs, int* __restrict__ bcur) {
    int b = threadIdx.x;
    if (b < NBUK) {
        int n0 = b * BNODES;
        bcur[b] = (n0 < NN) ? rs[n0] : NE;
    }
}

// pass 1: block-local binning by dst-bucket; packed (src | localdst<<17) run writes
__global__ __launch_bounds__(256) void k_pass1(
    const int* __restrict__ src, const int* __restrict__ dst,
    int* __restrict__ bcur, int* __restrict__ pairs) {
    __shared__ int cnt[NBUK];
    __shared__ int scanb[NBUK + 1];
    __shared__ int cur[NBUK];
    __shared__ int gbase[NBUK];
    __shared__ int pbuf[P1E];
    __shared__ unsigned char bsl[P1E];
    int t = threadIdx.x;
    int e0 = blockIdx.x * P1E;
    int m = NE - e0; if (m > P1E) m = P1E;
    cnt[t] = 0;
    __syncthreads();
    int ds[16], ss[16], bk[16];
#pragma unroll
    for (int j = 0; j < 16; ++j) {
        int e = t + j * 256;
        if (e < m) {
            ds[j] = dst[e0 + e];
            ss[j] = src[e0 + e];
            bk[j] = ds[j] / BNODES;
            atomicAdd(&cnt[bk[j]], 1);
        } else bk[j] = -1;
    }
    __syncthreads();
    int v = cnt[t];
    scanb[t] = v;
    __syncthreads();
    for (int off = 1; off < 256; off <<= 1) {
        int u = (t >= off) ? scanb[t - off] : 0;
        __syncthreads();
        scanb[t] += u;
        __syncthreads();
    }
    int excl = scanb[t] - v;
    scanb[t] = excl;
    cur[t] = excl;
    if (t == 255) scanb[256] = excl + v;
    __syncthreads();
#pragma unroll
    for (int j = 0; j < 16; ++j) {
        if (bk[j] >= 0) {
            int p = atomicAdd(&cur[bk[j]], 1);
            pbuf[p] = ss[j] | ((ds[j] - bk[j] * BNODES) << 17);
            bsl[p] = (unsigned char)bk[j];
        }
    }
    int cb = scanb[t + 1] - scanb[t];
    if (cb > 0) gbase[t] = atomicAdd(&bcur[t], cb);
    __syncthreads();
    for (int s = t; s < m; s += 256) {
        int b = bsl[s];
        pairs[gbase[b] + (s - scanb[b])] = pbuf[s];
    }
}

// pass 2: one block per bucket; build csr slice in LDS, stream out coalesced
__global__ __launch_bounds__(256) void k_pass2(
    const int* __restrict__ pairs, const int* __restrict__ rs,
    int* __restrict__ gcur, int* __restrict__ csr) {
    __shared__ int buf[BUFCAP];
    __shared__ int c[BNODES];
    int b = blockIdx.x;
    int n0 = b * BNODES;
    if (n0 >= NN) return;
    int n1 = n0 + BNODES; if (n1 > NN) n1 = NN;
    int t = threadIdx.x;
    int base = rs[n0];
    int end = (n1 >= NN) ? NE : rs[n1];
    int m = end - base;
    if (m <= BUFCAP) {
        for (int i = n0 + t; i < n1; i += 256) c[i - n0] = rs[i] - base;
        __syncthreads();
        for (int s = t; s < m; s += 256) {
            int pk = pairs[base + s];
            int p = atomicAdd(&c[(uint)pk >> 17], 1);
            buf[p] = pk & 0x1FFFF;
        }
        __syncthreads();
        for (int s = t; s < m; s += 256) csr[base + s] = buf[s];
    } else {
        for (int s = t; s < m; s += 256) {
            int pk = pairs[base + s];
            int p = atomicAdd(&gcur[n0 + ((uint)pk >> 17)], 1);
            csr[p] = pk & 0x1FFFF;
        }
    }
}

// ---------------- x prepack: [N,14] f32 -> [N,16] bf16 (8 uints/row) ----------------

__global__ void k_packx(const float* __restrict__ x, uint* __restrict__ xb) {
    int t = blockIdx.x * blockDim.x + threadIdx.x;
    if (t < NN * 8) {
        int row = t >> 3, q = t & 7;
        int j0 = 2 * q, j1 = 2 * q + 1;
        float f0 = (j0 < FIN) ? x[row * FIN + j0] : 0.f;
        float f1 = (j1 < FIN) ? x[row * FIN + j1] : 0.f;
        xb[t] = pack2bf16(f0, f1);
    }
}

// ---------------- Layer 1: xb16 -> hb16, 8-edge-parallel gather ----------------

__global__ __launch_bounds__(256) void k_layer1(
    const float* __restrict__ x, const uint* __restrict__ xb, uint* __restrict__ hbout,
    const float* __restrict__ Wl, const float* __restrict__ Wr, const float* __restrict__ b,
    const int* __restrict__ rs, const int* __restrict__ deg, const int* __restrict__ csr) {
    __shared__ float2 sW[FIN][HD];
    __shared__ float sb[HD];
    __shared__ float2 sAH[4][16];
    for (int i = threadIdx.x; i < FIN * HD; i += 256) {
        int k = i >> 6, j = i & 63;
        sW[k][j] = make_float2(Wl[i], Wr[i]);
    }
    if (threadIdx.x < HD) sb[threadIdx.x] = b[threadIdx.x];
    __syncthreads();
    int lane = threadIdx.x & 63, wid = threadIdx.x >> 6;
    int sub = lane >> 3;     // edge slot 0..7
    int fq = lane & 7;       // uint index in row (features 2fq,2fq+1)
    int ngroups = (NN + 3) / 4;
    for (int g = blockIdx.x; g < ngroups; g += gridDim.x) {
        int n = g * 4 + wid;
        bool act = n < NN;
        if (act) {
            int s0 = rs[n], d = deg[n];
            float2 a0 = make_float2(0.f, 0.f), a1 = a0, a2 = a0, a3 = a0;
            float2 a4 = a0, a5 = a0, a6 = a0, a7 = a0;
            for (int base = 0; base < d; base += 64) {
                int rem = d - base; if (rem > 64) rem = 64;
                int idxv = (lane < rem) ? csr[s0 + base + lane] : 0;
                int j = 0;
                for (; j + 64 <= rem; j += 64) {
                    int i0 = __shfl(idxv, j + 0 + sub);
                    int i1 = __shfl(idxv, j + 8 + sub);
                    int i2 = __shfl(idxv, j + 16 + sub);
                    int i3 = __shfl(idxv, j + 24 + sub);
                    int i4 = __shfl(idxv, j + 32 + sub);
                    int i5 = __shfl(idxv, j + 40 + sub);
                    int i6 = __shfl(idxv, j + 48 + sub);
                    int i7 = __shfl(idxv, j + 56 + sub);
                    uint u;
                    u = xb[(size_t)i0 * 8 + fq]; a0.x += bflo(u); a0.y += bfhi(u);
                    u = xb[(size_t)i1 * 8 + fq]; a1.x += bflo(u); a1.y += bfhi(u);
                    u = xb[(size_t)i2 * 8 + fq]; a2.x += bflo(u); a2.y += bfhi(u);
                    u = xb[(size_t)i3 * 8 + fq]; a3.x += bflo(u); a3.y += bfhi(u);
                    u = xb[(size_t)i4 * 8 + fq]; a4.x += bflo(u); a4.y += bfhi(u);
                    u = xb[(size_t)i5 * 8 + fq]; a5.x += bflo(u); a5.y += bfhi(u);
                    u = xb[(size_t)i6 * 8 + fq]; a6.x += bflo(u); a6.y += bfhi(u);
                    u = xb[(size_t)i7 * 8 + fq]; a7.x += bflo(u); a7.y += bfhi(u);
                }
                for (; j + 8 <= rem; j += 8) {
                    int i0 = __shfl(idxv, j + sub);
                    uint u = xb[(size_t)i0 * 8 + fq];
                    a0.x += bflo(u); a0.y += bfhi(u);
                }
                if (j < rem) {
                    int i0 = __shfl(idxv, j + sub);
                    if (sub < rem - j) {
                        uint u = xb[(size_t)i0 * 8 + fq];
                        a0.x += bflo(u); a0.y += bfhi(u);
                    }
                }
            }
            a0.x += a1.x + a2.x + a3.x + a4.x + a5.x + a6.x + a7.x;
            a0.y += a1.y + a2.y + a3.y + a4.y + a5.y + a6.y + a7.y;
            for (int off = 8; off <= 32; off <<= 1) {
                a0.x += __shfl_xor(a0.x, off);
                a0.y += __shfl_xor(a0.y, off);
            }
            float inv = 1.0f / (float)(deg[n] > 1 ? deg[n] : 1);
            // extract per-k values: k = lane (<14), src lane = k>>1, comp = k&1
            float e0 = __shfl(a0.x, lane >> 1);
            float e1 = __shfl(a0.y, lane >> 1);
            float sel = (lane & 1) ? e1 : e0;
            float xv = (lane < FIN) ? x[n * FIN + lane] : 0.f;
            if (lane < 16) sAH[wid][lane] = make_float2((lane < FIN) ? sel * inv : 0.f, xv);
        }
        __syncthreads();
        float out = sb[lane];
#pragma unroll
        for (int k = 0; k < FIN; ++k) {
            float2 w = sW[k][lane];
            float2 ah = sAH[wid][k];
            out += ah.x * w.x + ah.y * w.y;
        }
        out = fmaxf(out, 0.f);
        float o2 = __shfl_xor(out, 1);
        if (act && !(lane & 1)) hbout[(size_t)n * 32 + (lane >> 1)] = pack2bf16(out, o2);
        __syncthreads();
    }
}

// ---------------- H layers: bf16 gather (uint2), float2-packed dense ----------------

__device__ __forceinline__ void bfadd4(float4& A, uint2 U) {
    A.x += bflo(U.x); A.y += bfhi(U.x);
    A.z += bflo(U.y); A.w += bfhi(U.y);
}

template <bool FUSEZ>
__global__ __launch_bounds__(256) void k_layerH(
    const uint* __restrict__ hbin, uint* __restrict__ hbout,
    const float* __restrict__ Wl, const float* __restrict__ Wr, const float* __restrict__ b,
    const float* __restrict__ W4l, float* __restrict__ z,
    const int* __restrict__ rs, const int* __restrict__ deg, const int* __restrict__ csr) {
    __shared__ float2 sW[HD][HD];
    __shared__ float sb[HD], sW4l[HD * NC];
    __shared__ float2 sAH[4][HD];
    for (int i = threadIdx.x; i < HD * HD; i += 256) {
        int k = i >> 6, j = i & 63;
        sW[k][j] = make_float2(Wl[i], Wr[i]);
    }
    if (threadIdx.x < HD) sb[threadIdx.x] = b[threadIdx.x];
    if (FUSEZ && threadIdx.x < HD * NC) sW4l[threadIdx.x] = W4l[threadIdx.x];
    __syncthreads();
    const uint2* hb2 = (const uint2*)hbin;
    int lane = threadIdx.x & 63, wid = threadIdx.x >> 6;
    int sub = lane >> 4;       // edge slot 0..3
    int fq = lane & 15;        // uint2 index in row (features 4fq..4fq+3)
    int ngroups = (NN + 3) / 4;
    for (int g = blockIdx.x; g < ngroups; g += gridDim.x) {
        int n = g * 4 + wid;
        bool act = n < NN;
        float out;
        if (act) {
            int s0 = rs[n], d = deg[n];
            float4 A0 = make_float4(0.f, 0.f, 0.f, 0.f);
            float4 A1 = A0, A2 = A0, A3 = A0, A4 = A0, A5 = A0, A6 = A0, A7 = A0;
            for (int base = 0; base < d; base += 64) {
                int rem = d - base; if (rem > 64) rem = 64;
                int idxv = (lane < rem) ? csr[s0 + base + lane] : 0;
                int j = 0;
                for (; j + 32 <= rem; j += 32) {
                    int i0 = __shfl(idxv, j + 0 + sub);
                    int i1 = __shfl(idxv, j + 4 + sub);
                    int i2 = __shfl(idxv, j + 8 + sub);
                    int i3 = __shfl(idxv, j + 12 + sub);
                    int i4 = __shfl(idxv, j + 16 + sub);
                    int i5 = __shfl(idxv, j + 20 + sub);
                    int i6 = __shfl(idxv, j + 24 + sub);
                    int i7 = __shfl(idxv, j + 28 + sub);
                    bfadd4(A0, hb2[(size_t)i0 * 16 + fq]);
                    bfadd4(A1, hb2[(size_t)i1 * 16 + fq]);
                    bfadd4(A2, hb2[(size_t)i2 * 16 + fq]);
                    bfadd4(A3, hb2[(size_t)i3 * 16 + fq]);
                    bfadd4(A4, hb2[(size_t)i4 * 16 + fq]);
                    bfadd4(A5, hb2[(size_t)i5 * 16 + fq]);
                    bfadd4(A6, hb2[(size_t)i6 * 16 + fq]);
                    bfadd4(A7, hb2[(size_t)i7 * 16 + fq]);
                }
                for (; j + 4 <= rem; j += 4) {
                    int i0 = __shfl(idxv, j + sub);
                    bfadd4(A0, hb2[(size_t)i0 * 16 + fq]);
                }
                if (j < rem) {
                    int i0 = __shfl(idxv, j + sub);
                    if (sub < rem - j) bfadd4(A0, hb2[(size_t)i0 * 16 + fq]);
                }
            }
            A0.x += A1.x + A2.x + A3.x + A4.x + A5.x + A6.x + A7.x;
            A0.y += A1.y + A2.y + A3.y + A4.y + A5.y + A6.y + A7.y;
            A0.z += A1.z + A2.z + A3.z + A4.z + A5.z + A6.z + A7.z;
            A0.w += A1.w + A2.w + A3.w + A4.w + A5.w + A6.w + A7.w;
            for (int off = 16; off <= 32; off <<= 1) {
                A0.x += __shfl_xor(A0.x, off);
                A0.y += __shfl_xor(A0.y, off);
                A0.z += __shfl_xor(A0.z, off);
                A0.w += __shfl_xor(A0.w, off);
            }
            float inv = 1.0f / (float)(d > 1 ? d : 1);
            A0.x *= inv; A0.y *= inv; A0.z *= inv; A0.w *= inv;
            // self feature for k=lane
            uint hu = hbin[(size_t)n * 32 + (lane >> 1)];
            float hv = (lane & 1) ? bfhi(hu) : bflo(hu);
            // extract agg_k for k=lane: src=lane>>2, comp=lane&3
            float e0 = __shfl(A0.x, lane >> 2);
            float e1 = __shfl(A0.y, lane >> 2);
            float e2 = __shfl(A0.z, lane >> 2);
            float e3 = __shfl(A0.w, lane >> 2);
            int c = lane & 3;
            float sel = (c == 0) ? e0 : (c == 1) ? e1 : (c == 2) ? e2 : e3;
            sAH[wid][lane] = make_float2(sel, hv);
        }
        __syncthreads();
        out = sb[lane];
#pragma unroll 8
        for (int k = 0; k < HD; ++k) {
            float2 w = sW[k][lane];
            float2 ah = sAH[wid][k];
            out += ah.x * w.x + ah.y * w.y;
        }
        out = fmaxf(out, 0.f);
        float o2 = __shfl_xor(out, 1);
        if (act && !(lane & 1)) hbout[(size_t)n * 32 + (lane >> 1)] = pack2bf16(out, o2);
        if (FUSEZ) {
            float r0 = out * sW4l[lane * NC + 0];
            float r1 = out * sW4l[lane * NC + 1];
            for (int off = 32; off; off >>= 1) {
                r0 += __shfl_xor(r0, off);
                r1 += __shfl_xor(r1, off);
            }
            if (act && lane == 0) ((float2*)z)[n] = make_float2(r0, r1);
        }
        __syncthreads();
    }
}

// ---------------- Layer 4 + graph pooling sum ----------------

__global__ __launch_bounds__(256) void k_pool(
    const uint* __restrict__ h3, const float* __restrict__ z,
    const float* __restrict__ W4r, const float* __restrict__ b4,
    const int* __restrict__ rs, const int* __restrict__ deg, const int* __restrict__ csr,
    const int* __restrict__ batch, float* __restrict__ gsum) {
    __shared__ float sW[HD * NC];
    if (threadIdx.x < HD * NC) sW[threadIdx.x] = W4r[threadIdx.x];
    __syncthreads();
    const float2* z2 = (const float2*)z;
    int lane = threadIdx.x & 63, wid = threadIdx.x >> 6;
    int stride = gridDim.x * 4;
    for (int n = blockIdx.x * 4 + wid; n < NN; n += stride) {
        float r0 = 0.f, r1 = 0.f;
        if (lane < 32) {
            uint u = h3[(size_t)n * 32 + lane];
            float f0 = bflo(u), f1 = bfhi(u);
            r0 = f0 * sW[(2 * lane) * NC + 0] + f1 * sW[(2 * lane + 1) * NC + 0];
            r1 = f0 * sW[(2 * lane) * NC + 1] + f1 * sW[(2 * lane + 1) * NC + 1];
        }
        int s0 = rs[n], d = deg[n];
        float a0 = 0.f, a1 = 0.f;
        for (int j = lane; j < d; j += 64) {
            int s = csr[s0 + j];
            float2 zv = z2[s];
            a0 += zv.x;
            a1 += zv.y;
        }
        for (int off = 32; off; off >>= 1) {
            r0 += __shfl_xor(r0, off);
            r1 += __shfl_xor(r1, off);
            a0 += __shfl_xor(a0, off);
            a1 += __shfl_xor(a1, off);
        }
        if (lane == 0) {
            float inv = 1.0f / (float)(d > 1 ? d : 1);
            float o0 = a0 * inv + r0 + b4[0];
            float o1 = a1 * inv + r1 + b4[1];
            int gg = batch[n];
            atomicAdd(&gsum[gg * 2 + 0], o0);
            atomicAdd(&gsum[gg * 2 + 1], o1);
        }
    }
}

__global__ void k_final(const float* __restrict__ gsum, const int* __restrict__ gcnt,
                        float* __restrict__ out) {
    int g = blockIdx.x * blockDim.x + threadIdx.x;
    if (g < NG) {
        float inv = 1.0f / (float)(gcnt[g] > 1 ? gcnt[g] : 1);
        float p0 = gsum[g * 2 + 0] * inv;
        float p1 = gsum[g * 2 + 1] * inv;
        float m = fmaxf(p0, p1);
        float lse = m + logf(expf(p0 - m) + expf(p1 - m));
        out[g * 2 + 0] = p0 - lse;
        out[g * 2 + 1] = p1 - lse;
    }
}

// ---------------- launch ----------------

extern "C" void kernel_launch(void* const* d_in, const int* in_sizes, int n_in,
                              void* d_out, int out_size, void* d_ws, size_t ws_size,
                              hipStream_t stream) {
    const float* x   = (const float*)d_in[0];
    const float* W1l = (const float*)d_in[1];
    const float* W1r = (const float*)d_in[2];
    const float* b1  = (const float*)d_in[3];
    const float* W2l = (const float*)d_in[4];
    const float* W2r = (const float*)d_in[5];
    const float* b2  = (const float*)d_in[6];
    const float* W3l = (const float*)d_in[7];
    const float* W3r = (const float*)d_in[8];
    const float* b3  = (const float*)d_in[9];
    const float* W4l = (const float*)d_in[10];
    const float* W4r = (const float*)d_in[11];
    const float* b4  = (const float*)d_in[12];
    const int* ei    = (const int*)d_in[13];
    const int* batch = (const int*)d_in[14];
    const int* src = ei;
    const int* dst = ei + NE;
    float* out = (float*)d_out;

    char* w = (char*)d_ws;
    int* deg    = (int*)w; w += (size_t)NN * 4;
    int* rs     = (int*)w; w += (size_t)NN * 4;
    int* cursor = (int*)w; w += (size_t)NN * 4;
    int* csr    = (int*)w; w += (size_t)NE * 4;
    int* gcnt   = (int*)w; w += (size_t)NG * 4;
    int* bsums  = (int*)w; w += 512 * 4;
    int* bcur   = (int*)w; w += NBUK * 4;
    w = (char*)(((uintptr_t)w + 255) & ~(uintptr_t)255);
    uint* xb    = (uint*)w; w += (size_t)NN * 8 * 4;
    uint* hbA   = (uint*)w; w += (size_t)NN * 32 * 4;
    uint* hbB   = (uint*)w; w += (size_t)NN * 32 * 4;
    float* z    = (float*)w; w += (size_t)NN * NC * 4;
    float* gsum = (float*)w; w += (size_t)NG * NC * 4;
    int* pairs = (int*)hbB;  // alias: NE*4 == NN*32*4 bytes; dead before layer 2 writes hbB

    const int NB = (NN + 255) / 256;
    const int EB = (NE + 255) / 256;
    const int P1B = (NE + P1E - 1) / P1E;

    hipMemsetAsync(deg, 0, (size_t)NN * 4, stream);
    hipMemsetAsync(gcnt, 0, (size_t)NG * 4, stream);
    hipMemsetAsync(gsum, 0, (size_t)NG * NC * 4, stream);

    k_hist<<<EB, 256, 0, stream>>>(dst, deg, batch, gcnt);
    k_packx<<<(NN * 8 + 255) / 256, 256, 0, stream>>>(x, xb);
    k_scan1<<<NB, 256, 0, stream>>>(deg, rs, bsums, NN);
    k_scan2<<<1, 512, 0, stream>>>(bsums, NB);
    k_scan3<<<NB, 256, 0, stream>>>(deg, rs, cursor, bsums, NN);
    k_binit<<<1, 256, 0, stream>>>(rs, bcur);
    k_pass1<<<P1B, 256, 0, stream>>>(src, dst, bcur, pairs);
    k_pass2<<<NBUK, 256, 0, stream>>>(pairs, rs, cursor, csr);

    k_layer1<<<2048, 256, 0, stream>>>(x, xb, hbA, W1l, W1r, b1, rs, deg, csr);
    k_layerH<false><<<2048, 256, 0, stream>>>(hbA, hbB, W2l, W2r, b2, nullptr, nullptr, rs, deg, csr);
    k_layerH<true><<<2048, 256, 0, stream>>>(hbB, hbA, W3l, W3r, b3, W4l, z, rs, deg, csr);
    k_pool<<<2048, 256, 0, stream>>>(hbA, z, W4r, b4, rs, deg, csr, batch, gsum);
    k_final<<<(NG + 255) / 256, 256, 0, stream>>>(gsum, gcnt, out);
}

// Round 5
// 590.841 us; speedup vs baseline: 3.2146x; 1.1900x over previous
//
#include <hip/hip_runtime.h>

#define NN 100000
#define NE 3200000
#define NG 2000
#define FIN 14
#define HD 64
#define NC 2

#define NBUK 256
#define BNODES 391      // 256*391 = 100096 >= NN
#define P1E 4096        // edges per pass-1 block
#define BUFCAP 13312    // pass-2 LDS csr slice capacity

typedef unsigned int uint;

__device__ __forceinline__ uint pack2bf16(float a, float b) {
    uint ua = __float_as_uint(a), ub = __float_as_uint(b);
    ua = (ua + 0x7FFFu + ((ua >> 16) & 1u)) >> 16;
    ub = (ub + 0x7FFFu + ((ub >> 16) & 1u)) >> 16;
    return ua | (ub << 16);
}
__device__ __forceinline__ float bflo(uint u) { return __uint_as_float(u << 16); }
__device__ __forceinline__ float bfhi(uint u) { return __uint_as_float(u & 0xFFFF0000u); }

// ---------------- CSR build ----------------

__global__ void k_hist(const int* __restrict__ dst, int* __restrict__ deg,
                       const int* __restrict__ batch, int* __restrict__ gcnt) {
    int i = blockIdx.x * blockDim.x + threadIdx.x;
    if (i < NE) atomicAdd(&deg[dst[i]], 1);
    if (i < NN) atomicAdd(&gcnt[batch[i]], 1);
}

__global__ void k_scan1(const int* __restrict__ deg, int* __restrict__ incl,
                        int* __restrict__ bsums, int n) {
    __shared__ int tmp[256];
    int i = blockIdx.x * 256 + threadIdx.x;
    int v = (i < n) ? deg[i] : 0;
    tmp[threadIdx.x] = v;
    __syncthreads();
    for (int off = 1; off < 256; off <<= 1) {
        int t = (threadIdx.x >= off) ? tmp[threadIdx.x - off] : 0;
        __syncthreads();
        tmp[threadIdx.x] += t;
        __syncthreads();
    }
    if (i < n) incl[i] = tmp[threadIdx.x];
    if (threadIdx.x == 255) bsums[blockIdx.x] = tmp[255];
}

__global__ void k_scan2(int* bsums, int nb) {
    __shared__ int tmp[512];
    int t = threadIdx.x;
    int v = (t < nb) ? bsums[t] : 0;
    tmp[t] = v;
    __syncthreads();
    for (int off = 1; off < 512; off <<= 1) {
        int u = (t >= off) ? tmp[t - off] : 0;
        __syncthreads();
        tmp[t] += u;
        __syncthreads();
    }
    if (t < nb) bsums[t] = tmp[t] - v;  // exclusive
}

__global__ void k_scan3(const int* __restrict__ deg, int* __restrict__ rs,
                        int* __restrict__ cursor, const int* __restrict__ bsums, int n) {
    int i = blockIdx.x * 256 + threadIdx.x;
    if (i < n) {
        int v = rs[i] - deg[i] + bsums[blockIdx.x];
        rs[i] = v;
        cursor[i] = v;
    }
}

__global__ void k_binit(const int* __restrict__ rs, int* __restrict__ bcur) {
    int b = threadIdx.x;
    if (b < NBUK) {
        int n0 = b * BNODES;
        bcur[b] = (n0 < NN) ? rs[n0] : NE;
    }
}

// pass 1: block-local binning by dst-bucket; packed (src | localdst<<17) run writes
__global__ __launch_bounds__(256) void k_pass1(
    const int* __restrict__ src, const int* __restrict__ dst,
    int* __restrict__ bcur, int* __restrict__ pairs) {
    __shared__ int cnt[NBUK];
    __shared__ int scanb[NBUK + 1];
    __shared__ int cur[NBUK];
    __shared__ int gbase[NBUK];
    __shared__ int pbuf[P1E];
    __shared__ unsigned char bsl[P1E];
    int t = threadIdx.x;
    int e0 = blockIdx.x * P1E;
    int m = NE - e0; if (m > P1E) m = P1E;
    cnt[t] = 0;
    __syncthreads();
    int ds[16], ss[16], bk[16];
#pragma unroll
    for (int j = 0; j < 16; ++j) {
        int e = t + j * 256;
        if (e < m) {
            ds[j] = dst[e0 + e];
            ss[j] = src[e0 + e];
            bk[j] = ds[j] / BNODES;
            atomicAdd(&cnt[bk[j]], 1);
        } else bk[j] = -1;
    }
    __syncthreads();
    int v = cnt[t];
    scanb[t] = v;
    __syncthreads();
    for (int off = 1; off < 256; off <<= 1) {
        int u = (t >= off) ? scanb[t - off] : 0;
        __syncthreads();
        scanb[t] += u;
        __syncthreads();
    }
    int excl = scanb[t] - v;
    scanb[t] = excl;
    cur[t] = excl;
    if (t == 255) scanb[256] = excl + v;
    __syncthreads();
#pragma unroll
    for (int j = 0; j < 16; ++j) {
        if (bk[j] >= 0) {
            int p = atomicAdd(&cur[bk[j]], 1);
            pbuf[p] = ss[j] | ((ds[j] - bk[j] * BNODES) << 17);
            bsl[p] = (unsigned char)bk[j];
        }
    }
    int cb = scanb[t + 1] - scanb[t];
    if (cb > 0) gbase[t] = atomicAdd(&bcur[t], cb);
    __syncthreads();
    for (int s = t; s < m; s += 256) {
        int b = bsl[s];
        pairs[gbase[b] + (s - scanb[b])] = pbuf[s];
    }
}

// pass 2: one block per bucket; build csr slice in LDS, stream out coalesced
__global__ __launch_bounds__(256) void k_pass2(
    const int* __restrict__ pairs, const int* __restrict__ rs,
    int* __restrict__ gcur, int* __restrict__ csr) {
    __shared__ int buf[BUFCAP];
    __shared__ int c[BNODES];
    int b = blockIdx.x;
    int n0 = b * BNODES;
    if (n0 >= NN) return;
    int n1 = n0 + BNODES; if (n1 > NN) n1 = NN;
    int t = threadIdx.x;
    int base = rs[n0];
    int end = (n1 >= NN) ? NE : rs[n1];
    int m = end - base;
    if (m <= BUFCAP) {
        for (int i = n0 + t; i < n1; i += 256) c[i - n0] = rs[i] - base;
        __syncthreads();
        for (int s = t; s < m; s += 256) {
            int pk = pairs[base + s];
            int p = atomicAdd(&c[(uint)pk >> 17], 1);
            buf[p] = pk & 0x1FFFF;
        }
        __syncthreads();
        for (int s = t; s < m; s += 256) csr[base + s] = buf[s];
    } else {
        for (int s = t; s < m; s += 256) {
            int pk = pairs[base + s];
            int p = atomicAdd(&gcur[n0 + ((uint)pk >> 17)], 1);
            csr[p] = pk & 0x1FFFF;
        }
    }
}

// ---------------- x prepack: [N,14] f32 -> [N,16] bf16 (8 uints/row) ----------------

__global__ void k_packx(const float* __restrict__ x, uint* __restrict__ xb) {
    int t = blockIdx.x * blockDim.x + threadIdx.x;
    if (t < NN * 8) {
        int row = t >> 3, q = t & 7;
        int j0 = 2 * q, j1 = 2 * q + 1;
        float f0 = (j0 < FIN) ? x[row * FIN + j0] : 0.f;
        float f1 = (j1 < FIN) ? x[row * FIN + j1] : 0.f;
        xb[t] = pack2bf16(f0, f1);
    }
}

// ---------------- Layer 1: xb16 -> hb16, 8-edge-parallel gather, no in-loop barriers ----------------

__global__ __launch_bounds__(256, 6) void k_layer1(
    const float* __restrict__ x, const uint* __restrict__ xb, uint* __restrict__ hbout,
    const float* __restrict__ Wl, const float* __restrict__ Wr, const float* __restrict__ b,
    const int* __restrict__ rs, const int* __restrict__ deg, const int* __restrict__ csr) {
    __shared__ float2 sW[FIN][HD];
    __shared__ float sb[HD];
    __shared__ float2 sAH[4][16];
    for (int i = threadIdx.x; i < FIN * HD; i += 256) {
        int k = i >> 6, j = i & 63;
        sW[k][j] = make_float2(Wl[i], Wr[i]);
    }
    if (threadIdx.x < HD) sb[threadIdx.x] = b[threadIdx.x];
    __syncthreads();
    int lane = threadIdx.x & 63, wid = threadIdx.x >> 6;
    int sub = lane >> 3;     // edge slot 0..7
    int fq = lane & 7;       // uint index in row (features 2fq,2fq+1)
    int ngroups = (NN + 3) / 4;
    for (int g = blockIdx.x; g < ngroups; g += gridDim.x) {
        int n = g * 4 + wid;
        bool act = n < NN;
        if (act) {
            int s0 = rs[n], d = deg[n];
            float xv = (lane < FIN) ? x[n * FIN + lane] : 0.f;
            float2 a0 = make_float2(0.f, 0.f), a1 = a0, a2 = a0, a3 = a0;
            float2 a4 = a0, a5 = a0, a6 = a0, a7 = a0;
            for (int base = 0; base < d; base += 64) {
                int rem = d - base; if (rem > 64) rem = 64;
                int idxv = (lane < rem) ? csr[s0 + base + lane] : 0;
                int j = 0;
                for (; j + 64 <= rem; j += 64) {
                    int i0 = __shfl(idxv, j + 0 + sub);
                    int i1 = __shfl(idxv, j + 8 + sub);
                    int i2 = __shfl(idxv, j + 16 + sub);
                    int i3 = __shfl(idxv, j + 24 + sub);
                    int i4 = __shfl(idxv, j + 32 + sub);
                    int i5 = __shfl(idxv, j + 40 + sub);
                    int i6 = __shfl(idxv, j + 48 + sub);
                    int i7 = __shfl(idxv, j + 56 + sub);
                    uint u;
                    u = xb[(size_t)i0 * 8 + fq]; a0.x += bflo(u); a0.y += bfhi(u);
                    u = xb[(size_t)i1 * 8 + fq]; a1.x += bflo(u); a1.y += bfhi(u);
                    u = xb[(size_t)i2 * 8 + fq]; a2.x += bflo(u); a2.y += bfhi(u);
                    u = xb[(size_t)i3 * 8 + fq]; a3.x += bflo(u); a3.y += bfhi(u);
                    u = xb[(size_t)i4 * 8 + fq]; a4.x += bflo(u); a4.y += bfhi(u);
                    u = xb[(size_t)i5 * 8 + fq]; a5.x += bflo(u); a5.y += bfhi(u);
                    u = xb[(size_t)i6 * 8 + fq]; a6.x += bflo(u); a6.y += bfhi(u);
                    u = xb[(size_t)i7 * 8 + fq]; a7.x += bflo(u); a7.y += bfhi(u);
                }
                for (; j + 8 <= rem; j += 8) {
                    int i0 = __shfl(idxv, j + sub);
                    uint u = xb[(size_t)i0 * 8 + fq];
                    a0.x += bflo(u); a0.y += bfhi(u);
                }
                if (j < rem) {
                    int i0 = __shfl(idxv, j + sub);
                    if (sub < rem - j) {
                        uint u = xb[(size_t)i0 * 8 + fq];
                        a0.x += bflo(u); a0.y += bfhi(u);
                    }
                }
            }
            a0.x += a1.x + a2.x + a3.x + a4.x + a5.x + a6.x + a7.x;
            a0.y += a1.y + a2.y + a3.y + a4.y + a5.y + a6.y + a7.y;
            for (int off = 8; off <= 32; off <<= 1) {
                a0.x += __shfl_xor(a0.x, off);
                a0.y += __shfl_xor(a0.y, off);
            }
            float inv = 1.0f / (float)(d > 1 ? d : 1);
            float e0 = __shfl(a0.x, lane >> 1);
            float e1 = __shfl(a0.y, lane >> 1);
            float sel = (lane & 1) ? e1 : e0;
            if (lane < 16) sAH[wid][lane] = make_float2((lane < FIN) ? sel * inv : 0.f, xv);
        }
        // no barrier: sAH[wid] is per-wave scratch (same-wave RAW ordered by lgkmcnt)
        float out = sb[lane];
#pragma unroll
        for (int k = 0; k < FIN; ++k) {
            float2 w = sW[k][lane];
            float2 ah = sAH[wid][k];
            out += ah.x * w.x + ah.y * w.y;
        }
        out = fmaxf(out, 0.f);
        float o2 = __shfl_xor(out, 1);
        if (act && !(lane & 1)) hbout[(size_t)n * 32 + (lane >> 1)] = pack2bf16(out, o2);
    }
}

// ---------------- H layers: bf16 gather, bf16-packed weights, no in-loop barriers ----------------

__device__ __forceinline__ void bfadd4(float4& A, uint2 U) {
    A.x += bflo(U.x); A.y += bfhi(U.x);
    A.z += bflo(U.y); A.w += bfhi(U.y);
}

template <bool FUSEZ>
__global__ __launch_bounds__(256, 6) void k_layerH(
    const uint* __restrict__ hbin, uint* __restrict__ hbout,
    const float* __restrict__ Wl, const float* __restrict__ Wr, const float* __restrict__ b,
    const float* __restrict__ W4l, float* __restrict__ z,
    const int* __restrict__ rs, const int* __restrict__ deg, const int* __restrict__ csr) {
    __shared__ uint sWp[HD][HD];        // {Wl,Wr}[k][j] packed bf16 lo/hi: 16 KB
    __shared__ float sb[HD], sW4l[HD * NC];
    __shared__ float2 sAH[4][HD];       // per-wave scratch
    for (int i = threadIdx.x; i < HD * HD; i += 256) {
        int k = i >> 6, j = i & 63;
        sWp[k][j] = pack2bf16(Wl[i], Wr[i]);
    }
    if (threadIdx.x < HD) sb[threadIdx.x] = b[threadIdx.x];
    if (FUSEZ && threadIdx.x < HD * NC) sW4l[threadIdx.x] = W4l[threadIdx.x];
    __syncthreads();
    const uint2* hb2 = (const uint2*)hbin;
    int lane = threadIdx.x & 63, wid = threadIdx.x >> 6;
    int sub = lane >> 4;       // edge slot 0..3
    int fq = lane & 15;        // uint2 index in row (features 4fq..4fq+3)
    int ngroups = (NN + 3) / 4;
    for (int g = blockIdx.x; g < ngroups; g += gridDim.x) {
        int n = g * 4 + wid;
        bool act = n < NN;
        if (act) {
            int s0 = rs[n], d = deg[n];
            uint hu = hbin[(size_t)n * 32 + (lane >> 1)];   // self feature, hoisted
            float hv = (lane & 1) ? bfhi(hu) : bflo(hu);
            float4 A0 = make_float4(0.f, 0.f, 0.f, 0.f);
            float4 A1 = A0, A2 = A0, A3 = A0, A4 = A0, A5 = A0, A6 = A0, A7 = A0;
            for (int base = 0; base < d; base += 64) {
                int rem = d - base; if (rem > 64) rem = 64;
                int idxv = (lane < rem) ? csr[s0 + base + lane] : 0;
                int j = 0;
                for (; j + 32 <= rem; j += 32) {
                    int i0 = __shfl(idxv, j + 0 + sub);
                    int i1 = __shfl(idxv, j + 4 + sub);
                    int i2 = __shfl(idxv, j + 8 + sub);
                    int i3 = __shfl(idxv, j + 12 + sub);
                    int i4 = __shfl(idxv, j + 16 + sub);
                    int i5 = __shfl(idxv, j + 20 + sub);
                    int i6 = __shfl(idxv, j + 24 + sub);
                    int i7 = __shfl(idxv, j + 28 + sub);
                    bfadd4(A0, hb2[(size_t)i0 * 16 + fq]);
                    bfadd4(A1, hb2[(size_t)i1 * 16 + fq]);
                    bfadd4(A2, hb2[(size_t)i2 * 16 + fq]);
                    bfadd4(A3, hb2[(size_t)i3 * 16 + fq]);
                    bfadd4(A4, hb2[(size_t)i4 * 16 + fq]);
                    bfadd4(A5, hb2[(size_t)i5 * 16 + fq]);
                    bfadd4(A6, hb2[(size_t)i6 * 16 + fq]);
                    bfadd4(A7, hb2[(size_t)i7 * 16 + fq]);
                }
                for (; j + 4 <= rem; j += 4) {
                    int i0 = __shfl(idxv, j + sub);
                    bfadd4(A0, hb2[(size_t)i0 * 16 + fq]);
                }
                if (j < rem) {
                    int i0 = __shfl(idxv, j + sub);
                    if (sub < rem - j) bfadd4(A0, hb2[(size_t)i0 * 16 + fq]);
                }
            }
            A0.x += A1.x + A2.x + A3.x + A4.x + A5.x + A6.x + A7.x;
            A0.y += A1.y + A2.y + A3.y + A4.y + A5.y + A6.y + A7.y;
            A0.z += A1.z + A2.z + A3.z + A4.z + A5.z + A6.z + A7.z;
            A0.w += A1.w + A2.w + A3.w + A4.w + A5.w + A6.w + A7.w;
            for (int off = 16; off <= 32; off <<= 1) {
                A0.x += __shfl_xor(A0.x, off);
                A0.y += __shfl_xor(A0.y, off);
                A0.z += __shfl_xor(A0.z, off);
                A0.w += __shfl_xor(A0.w, off);
            }
            float inv = 1.0f / (float)(d > 1 ? d : 1);
            A0.x *= inv; A0.y *= inv; A0.z *= inv; A0.w *= inv;
            float e0 = __shfl(A0.x, lane >> 2);
            float e1 = __shfl(A0.y, lane >> 2);
            float e2 = __shfl(A0.z, lane >> 2);
            float e3 = __shfl(A0.w, lane >> 2);
            int c = lane & 3;
            float sel = (c == 0) ? e0 : (c == 1) ? e1 : (c == 2) ? e2 : e3;
            sAH[wid][lane] = make_float2(sel, hv);
        }
        // no barrier: sAH[wid] is per-wave scratch
        float out = sb[lane];
#pragma unroll 8
        for (int k = 0; k < HD; ++k) {
            uint wu = sWp[k][lane];
            float2 ah = sAH[wid][k];
            out += ah.x * bflo(wu) + ah.y * bfhi(wu);
        }
        out = fmaxf(out, 0.f);
        float o2 = __shfl_xor(out, 1);
        if (act && !(lane & 1)) hbout[(size_t)n * 32 + (lane >> 1)] = pack2bf16(out, o2);
        if (FUSEZ) {
            float r0 = out * sW4l[lane * NC + 0];
            float r1 = out * sW4l[lane * NC + 1];
            for (int off = 32; off; off >>= 1) {
                r0 += __shfl_xor(r0, off);
                r1 += __shfl_xor(r1, off);
            }
            if (act && lane == 0) ((float2*)z)[n] = make_float2(r0, r1);
        }
    }
}

// ---------------- Layer 4 + graph pooling sum ----------------

__global__ __launch_bounds__(256) void k_pool(
    const uint* __restrict__ h3, const float* __restrict__ z,
    const float* __restrict__ W4r, const float* __restrict__ b4,
    const int* __restrict__ rs, const int* __restrict__ deg, const int* __restrict__ csr,
    const int* __restrict__ batch, float* __restrict__ gsum) {
    __shared__ float sW[HD * NC];
    if (threadIdx.x < HD * NC) sW[threadIdx.x] = W4r[threadIdx.x];
    __syncthreads();
    const float2* z2 = (const float2*)z;
    int lane = threadIdx.x & 63, wid = threadIdx.x >> 6;
    int stride = gridDim.x * 4;
    for (int n = blockIdx.x * 4 + wid; n < NN; n += stride) {
        float r0 = 0.f, r1 = 0.f;
        if (lane < 32) {
            uint u = h3[(size_t)n * 32 + lane];
            float f0 = bflo(u), f1 = bfhi(u);
            r0 = f0 * sW[(2 * lane) * NC + 0] + f1 * sW[(2 * lane + 1) * NC + 0];
            r1 = f0 * sW[(2 * lane) * NC + 1] + f1 * sW[(2 * lane + 1) * NC + 1];
        }
        int s0 = rs[n], d = deg[n];
        float a0 = 0.f, a1 = 0.f;
        for (int j = lane; j < d; j += 64) {
            int s = csr[s0 + j];
            float2 zv = z2[s];
            a0 += zv.x;
            a1 += zv.y;
        }
        for (int off = 32; off; off >>= 1) {
            r0 += __shfl_xor(r0, off);
            r1 += __shfl_xor(r1, off);
            a0 += __shfl_xor(a0, off);
            a1 += __shfl_xor(a1, off);
        }
        if (lane == 0) {
            float inv = 1.0f / (float)(d > 1 ? d : 1);
            float o0 = a0 * inv + r0 + b4[0];
            float o1 = a1 * inv + r1 + b4[1];
            int gg = batch[n];
            atomicAdd(&gsum[gg * 2 + 0], o0);
            atomicAdd(&gsum[gg * 2 + 1], o1);
        }
    }
}

__global__ void k_final(const float* __restrict__ gsum, const int* __restrict__ gcnt,
                        float* __restrict__ out) {
    int g = blockIdx.x * blockDim.x + threadIdx.x;
    if (g < NG) {
        float inv = 1.0f / (float)(gcnt[g] > 1 ? gcnt[g] : 1);
        float p0 = gsum[g * 2 + 0] * inv;
        float p1 = gsum[g * 2 + 1] * inv;
        float m = fmaxf(p0, p1);
        float lse = m + logf(expf(p0 - m) + expf(p1 - m));
        out[g * 2 + 0] = p0 - lse;
        out[g * 2 + 1] = p1 - lse;
    }
}

// ---------------- launch ----------------

extern "C" void kernel_launch(void* const* d_in, const int* in_sizes, int n_in,
                              void* d_out, int out_size, void* d_ws, size_t ws_size,
                              hipStream_t stream) {
    const float* x   = (const float*)d_in[0];
    const float* W1l = (const float*)d_in[1];
    const float* W1r = (const float*)d_in[2];
    const float* b1  = (const float*)d_in[3];
    const float* W2l = (const float*)d_in[4];
    const float* W2r = (const float*)d_in[5];
    const float* b2  = (const float*)d_in[6];
    const float* W3l = (const float*)d_in[7];
    const float* W3r = (const float*)d_in[8];
    const float* b3  = (const float*)d_in[9];
    const float* W4l = (const float*)d_in[10];
    const float* W4r = (const float*)d_in[11];
    const float* b4  = (const float*)d_in[12];
    const int* ei    = (const int*)d_in[13];
    const int* batch = (const int*)d_in[14];
    const int* src = ei;
    const int* dst = ei + NE;
    float* out = (float*)d_out;

    char* w = (char*)d_ws;
    int* deg    = (int*)w; w += (size_t)NN * 4;
    int* rs     = (int*)w; w += (size_t)NN * 4;
    int* cursor = (int*)w; w += (size_t)NN * 4;
    int* csr    = (int*)w; w += (size_t)NE * 4;
    int* gcnt   = (int*)w; w += (size_t)NG * 4;
    int* bsums  = (int*)w; w += 512 * 4;
    int* bcur   = (int*)w; w += NBUK * 4;
    w = (char*)(((uintptr_t)w + 255) & ~(uintptr_t)255);
    uint* xb    = (uint*)w; w += (size_t)NN * 8 * 4;
    uint* hbA   = (uint*)w; w += (size_t)NN * 32 * 4;
    uint* hbB   = (uint*)w; w += (size_t)NN * 32 * 4;
    float* z    = (float*)w; w += (size_t)NN * NC * 4;
    float* gsum = (float*)w; w += (size_t)NG * NC * 4;
    int* pairs = (int*)hbB;  // alias: NE*4 == NN*32*4 bytes; dead before layer 2 writes hbB

    const int NB = (NN + 255) / 256;
    const int EB = (NE + 255) / 256;
    const int P1B = (NE + P1E - 1) / P1E;

    hipMemsetAsync(deg, 0, (size_t)NN * 4, stream);
    hipMemsetAsync(gcnt, 0, (size_t)NG * 4, stream);
    hipMemsetAsync(gsum, 0, (size_t)NG * NC * 4, stream);

    k_hist<<<EB, 256, 0, stream>>>(dst, deg, batch, gcnt);
    k_packx<<<(NN * 8 + 255) / 256, 256, 0, stream>>>(x, xb);
    k_scan1<<<NB, 256, 0, stream>>>(deg, rs, bsums, NN);
    k_scan2<<<1, 512, 0, stream>>>(bsums, NB);
    k_scan3<<<NB, 256, 0, stream>>>(deg, rs, cursor, bsums, NN);
    k_binit<<<1, 256, 0, stream>>>(rs, bcur);
    k_pass1<<<P1B, 256, 0, stream>>>(src, dst, bcur, pairs);
    k_pass2<<<NBUK, 256, 0, stream>>>(pairs, rs, cursor, csr);

    k_layer1<<<1536, 256, 0, stream>>>(x, xb, hbA, W1l, W1r, b1, rs, deg, csr);
    k_layerH<false><<<1536, 256, 0, stream>>>(hbA, hbB, W2l, W2r, b2, nullptr, nullptr, rs, deg, csr);
    k_layerH<true><<<1536, 256, 0, stream>>>(hbB, hbA, W3l, W3r, b3, W4l, z, rs, deg, csr);
    k_pool<<<2048, 256, 0, stream>>>(hbA, z, W4r, b4, rs, deg, csr, batch, gsum);
    k_final<<<(NG + 255) / 256, 256, 0, stream>>>(gsum, gcnt, out);
}

// Round 6
// 468.517 us; speedup vs baseline: 4.0539x; 1.2611x over previous
//
#include <hip/hip_runtime.h>

#define NN 100000
#define NE 3200000
#define NG 2000
#define FIN 14
#define HD 64
#define NC 2

#define NBUK 256
#define BNODES 391      // 256*391 = 100096 >= NN
#define P1E 4096        // edges per pass-1 block
#define BUFCAP 13312    // pass-2 LDS csr slice capacity (mean 12500, +7 sigma)

typedef unsigned int uint;

__device__ __forceinline__ uint pack2bf16(float a, float b) {
    uint ua = __float_as_uint(a), ub = __float_as_uint(b);
    ua = (ua + 0x7FFFu + ((ua >> 16) & 1u)) >> 16;
    ub = (ub + 0x7FFFu + ((ub >> 16) & 1u)) >> 16;
    return ua | (ub << 16);
}
__device__ __forceinline__ float bflo(uint u) { return __uint_as_float(u << 16); }
__device__ __forceinline__ float bfhi(uint u) { return __uint_as_float(u & 0xFFFF0000u); }

// ---------------- bucket histogram (LDS-privatized) ----------------

__global__ __launch_bounds__(256) void k_hist_bucket(const int* __restrict__ dst,
                                                     int* __restrict__ bkcnt) {
    __shared__ int cnt[NBUK];
    int t = threadIdx.x;
    cnt[t] = 0;
    __syncthreads();
    int e0 = blockIdx.x * P1E;
    int m = NE - e0; if (m > P1E) m = P1E;
    for (int e = t; e < m; e += 256) atomicAdd(&cnt[dst[e0 + e] / BNODES], 1);
    __syncthreads();
    if (cnt[t] > 0) atomicAdd(&bkcnt[t], cnt[t]);
}

// exclusive scan of 256 bucket counts -> bbase[257]; also init bcur
__global__ void k_scanb(const int* __restrict__ bkcnt, int* __restrict__ bbase,
                        int* __restrict__ bcur) {
    __shared__ int tmp[NBUK];
    int t = threadIdx.x;
    int v = bkcnt[t];
    tmp[t] = v;
    __syncthreads();
    for (int off = 1; off < NBUK; off <<= 1) {
        int u = (t >= off) ? tmp[t - off] : 0;
        __syncthreads();
        tmp[t] += u;
        __syncthreads();
    }
    int excl = tmp[t] - v;
    bbase[t] = excl;
    bcur[t] = excl;
    if (t == NBUK - 1) bbase[NBUK] = tmp[t];
}

// graph boundaries from sorted batch (replaces atomic gcnt)
__global__ void k_gbounds(const int* __restrict__ batch, int* __restrict__ gstart,
                          int* __restrict__ gend) {
    int i = blockIdx.x * blockDim.x + threadIdx.x;
    if (i < NN) {
        int b = batch[i];
        if (i == 0 || batch[i - 1] != b) gstart[b] = i;
        if (i == NN - 1 || batch[i + 1] != b) gend[b] = i + 1;
    }
}

// pass 1: block-local binning by dst-bucket; packed (src | localdst<<17) run writes
__global__ __launch_bounds__(256) void k_pass1(
    const int* __restrict__ src, const int* __restrict__ dst,
    int* __restrict__ bcur, int* __restrict__ pairs) {
    __shared__ int cnt[NBUK];
    __shared__ int scanb[NBUK + 1];
    __shared__ int cur[NBUK];
    __shared__ int gbase[NBUK];
    __shared__ int pbuf[P1E];
    __shared__ unsigned char bsl[P1E];
    int t = threadIdx.x;
    int e0 = blockIdx.x * P1E;
    int m = NE - e0; if (m > P1E) m = P1E;
    cnt[t] = 0;
    __syncthreads();
    int ds[16], ss[16], bk[16];
#pragma unroll
    for (int j = 0; j < 16; ++j) {
        int e = t + j * 256;
        if (e < m) {
            ds[j] = dst[e0 + e];
            ss[j] = src[e0 + e];
            bk[j] = ds[j] / BNODES;
            atomicAdd(&cnt[bk[j]], 1);
        } else bk[j] = -1;
    }
    __syncthreads();
    int v = cnt[t];
    scanb[t] = v;
    __syncthreads();
    for (int off = 1; off < 256; off <<= 1) {
        int u = (t >= off) ? scanb[t - off] : 0;
        __syncthreads();
        scanb[t] += u;
        __syncthreads();
    }
    int excl = scanb[t] - v;
    scanb[t] = excl;
    cur[t] = excl;
    if (t == 255) scanb[256] = excl + v;
    __syncthreads();
#pragma unroll
    for (int j = 0; j < 16; ++j) {
        if (bk[j] >= 0) {
            int p = atomicAdd(&cur[bk[j]], 1);
            pbuf[p] = ss[j] | ((ds[j] - bk[j] * BNODES) << 17);
            bsl[p] = (unsigned char)bk[j];
        }
    }
    int cb = scanb[t + 1] - scanb[t];
    if (cb > 0) gbase[t] = atomicAdd(&bcur[t], cb);
    __syncthreads();
    for (int s = t; s < m; s += 256) {
        int b = bsl[s];
        pairs[gbase[b] + (s - scanb[b])] = pbuf[s];
    }
}

// pass 2: one block per bucket. LDS: hist -> scan -> deg/rs out, scatter -> csr out.
__global__ __launch_bounds__(256) void k_pass2(
    const int* __restrict__ pairs, const int* __restrict__ bbase,
    int* __restrict__ deg, int* __restrict__ rs, int* __restrict__ csr) {
    __shared__ int buf1[BUFCAP];
    __shared__ int buf2[BUFCAP];
    __shared__ int cnt[512];
    __shared__ int rsl[512];
    __shared__ int cur[512];
    __shared__ int s1[256];
    int b = blockIdx.x;
    int n0 = b * BNODES;
    if (n0 >= NN) return;
    int nlocal = NN - n0; if (nlocal > BNODES) nlocal = BNODES;
    int t = threadIdx.x;
    int base = bbase[b];
    int m = bbase[b + 1] - base;
    bool fits = (m <= BUFCAP);
    cnt[t] = 0; cnt[t + 256] = 0;
    __syncthreads();
    for (int s = t; s < m; s += 256) {
        int pk = pairs[base + s];
        if (fits) buf1[s] = pk;
        atomicAdd(&cnt[(uint)pk >> 17], 1);
    }
    __syncthreads();
    // scan 512 entries with 256 threads (pair-sums + Hillis-Steele)
    int c0 = cnt[2 * t], c1 = cnt[2 * t + 1];
    int ps = c0 + c1;
    s1[t] = ps;
    __syncthreads();
    for (int off = 1; off < 256; off <<= 1) {
        int u = (t >= off) ? s1[t - off] : 0;
        __syncthreads();
        s1[t] += u;
        __syncthreads();
    }
    int pexcl = s1[t] - ps;
    rsl[2 * t] = pexcl;       cur[2 * t] = pexcl;
    rsl[2 * t + 1] = pexcl + c0; cur[2 * t + 1] = pexcl + c0;
    __syncthreads();
    for (int i = t; i < nlocal; i += 256) {
        deg[n0 + i] = cnt[i];
        rs[n0 + i] = base + rsl[i];
    }
    if (fits) {
        for (int s = t; s < m; s += 256) {
            int pk = buf1[s];
            int p = atomicAdd(&cur[(uint)pk >> 17], 1);
            buf2[p] = pk & 0x1FFFF;
        }
        __syncthreads();
        for (int s = t; s < m; s += 256) csr[base + s] = buf2[s];
    } else {
        for (int s = t; s < m; s += 256) {
            int pk = pairs[base + s];
            int p = atomicAdd(&cur[(uint)pk >> 17], 1);
            csr[base + p] = pk & 0x1FFFF;
        }
    }
}

// ---------------- x prepack: [N,14] f32 -> [N,16] bf16 (8 uints/row) ----------------

__global__ void k_packx(const float* __restrict__ x, uint* __restrict__ xb) {
    int t = blockIdx.x * blockDim.x + threadIdx.x;
    if (t < NN * 8) {
        int row = t >> 3, q = t & 7;
        int j0 = 2 * q, j1 = 2 * q + 1;
        float f0 = (j0 < FIN) ? x[row * FIN + j0] : 0.f;
        float f1 = (j1 < FIN) ? x[row * FIN + j1] : 0.f;
        xb[t] = pack2bf16(f0, f1);
    }
}

// ---------------- Layer 1: xb16 -> hb16, 8-edge-parallel gather, no in-loop barriers ----------------

__global__ __launch_bounds__(256, 6) void k_layer1(
    const float* __restrict__ x, const uint* __restrict__ xb, uint* __restrict__ hbout,
    const float* __restrict__ Wl, const float* __restrict__ Wr, const float* __restrict__ b,
    const int* __restrict__ rs, const int* __restrict__ deg, const int* __restrict__ csr) {
    __shared__ float2 sW[FIN][HD];
    __shared__ float sb[HD];
    __shared__ float2 sAH[4][16];
    for (int i = threadIdx.x; i < FIN * HD; i += 256) {
        int k = i >> 6, j = i & 63;
        sW[k][j] = make_float2(Wl[i], Wr[i]);
    }
    if (threadIdx.x < HD) sb[threadIdx.x] = b[threadIdx.x];
    __syncthreads();
    int lane = threadIdx.x & 63, wid = threadIdx.x >> 6;
    int sub = lane >> 3;     // edge slot 0..7
    int fq = lane & 7;       // uint index in row (features 2fq,2fq+1)
    int ngroups = (NN + 3) / 4;
    for (int g = blockIdx.x; g < ngroups; g += gridDim.x) {
        int n = g * 4 + wid;
        bool act = n < NN;
        if (act) {
            int s0 = rs[n], d = deg[n];
            float xv = (lane < FIN) ? x[n * FIN + lane] : 0.f;
            float2 a0 = make_float2(0.f, 0.f), a1 = a0, a2 = a0, a3 = a0;
            float2 a4 = a0, a5 = a0, a6 = a0, a7 = a0;
            for (int base = 0; base < d; base += 64) {
                int rem = d - base; if (rem > 64) rem = 64;
                int idxv = (lane < rem) ? csr[s0 + base + lane] : 0;
                int j = 0;
                for (; j + 64 <= rem; j += 64) {
                    int i0 = __shfl(idxv, j + 0 + sub);
                    int i1 = __shfl(idxv, j + 8 + sub);
                    int i2 = __shfl(idxv, j + 16 + sub);
                    int i3 = __shfl(idxv, j + 24 + sub);
                    int i4 = __shfl(idxv, j + 32 + sub);
                    int i5 = __shfl(idxv, j + 40 + sub);
                    int i6 = __shfl(idxv, j + 48 + sub);
                    int i7 = __shfl(idxv, j + 56 + sub);
                    uint u;
                    u = xb[(size_t)i0 * 8 + fq]; a0.x += bflo(u); a0.y += bfhi(u);
                    u = xb[(size_t)i1 * 8 + fq]; a1.x += bflo(u); a1.y += bfhi(u);
                    u = xb[(size_t)i2 * 8 + fq]; a2.x += bflo(u); a2.y += bfhi(u);
                    u = xb[(size_t)i3 * 8 + fq]; a3.x += bflo(u); a3.y += bfhi(u);
                    u = xb[(size_t)i4 * 8 + fq]; a4.x += bflo(u); a4.y += bfhi(u);
                    u = xb[(size_t)i5 * 8 + fq]; a5.x += bflo(u); a5.y += bfhi(u);
                    u = xb[(size_t)i6 * 8 + fq]; a6.x += bflo(u); a6.y += bfhi(u);
                    u = xb[(size_t)i7 * 8 + fq]; a7.x += bflo(u); a7.y += bfhi(u);
                }
                for (; j + 8 <= rem; j += 8) {
                    int i0 = __shfl(idxv, j + sub);
                    uint u = xb[(size_t)i0 * 8 + fq];
                    a0.x += bflo(u); a0.y += bfhi(u);
                }
                if (j < rem) {
                    int i0 = __shfl(idxv, j + sub);
                    if (sub < rem - j) {
                        uint u = xb[(size_t)i0 * 8 + fq];
                        a0.x += bflo(u); a0.y += bfhi(u);
                    }
                }
            }
            a0.x += a1.x + a2.x + a3.x + a4.x + a5.x + a6.x + a7.x;
            a0.y += a1.y + a2.y + a3.y + a4.y + a5.y + a6.y + a7.y;
            for (int off = 8; off <= 32; off <<= 1) {
                a0.x += __shfl_xor(a0.x, off);
                a0.y += __shfl_xor(a0.y, off);
            }
            float inv = 1.0f / (float)(d > 1 ? d : 1);
            float e0 = __shfl(a0.x, lane >> 1);
            float e1 = __shfl(a0.y, lane >> 1);
            float sel = (lane & 1) ? e1 : e0;
            if (lane < 16) sAH[wid][lane] = make_float2((lane < FIN) ? sel * inv : 0.f, xv);
        }
        // no barrier: sAH[wid] is per-wave scratch (same-wave LDS RAW ordered by lgkmcnt)
        float out = sb[lane];
#pragma unroll
        for (int k = 0; k < FIN; ++k) {
            float2 w = sW[k][lane];
            float2 ah = sAH[wid][k];
            out += ah.x * w.x + ah.y * w.y;
        }
        out = fmaxf(out, 0.f);
        float o2 = __shfl_xor(out, 1);
        if (act && !(lane & 1)) hbout[(size_t)n * 32 + (lane >> 1)] = pack2bf16(out, o2);
    }
}

// ---------------- H layers: bf16 gather, bf16-packed weights, no in-loop barriers ----------------

__device__ __forceinline__ void bfadd4(float4& A, uint2 U) {
    A.x += bflo(U.x); A.y += bfhi(U.x);
    A.z += bflo(U.y); A.w += bfhi(U.y);
}

template <bool FUSEZ>
__global__ __launch_bounds__(256, 6) void k_layerH(
    const uint* __restrict__ hbin, uint* __restrict__ hbout,
    const float* __restrict__ Wl, const float* __restrict__ Wr, const float* __restrict__ b,
    const float* __restrict__ W4l, float* __restrict__ z,
    const int* __restrict__ rs, const int* __restrict__ deg, const int* __restrict__ csr) {
    __shared__ uint sWp[HD][HD];        // {Wl,Wr}[k][j] packed bf16 lo/hi: 16 KB
    __shared__ float sb[HD], sW4l[HD * NC];
    __shared__ float2 sAH[4][HD];       // per-wave scratch
    for (int i = threadIdx.x; i < HD * HD; i += 256) {
        int k = i >> 6, j = i & 63;
        sWp[k][j] = pack2bf16(Wl[i], Wr[i]);
    }
    if (threadIdx.x < HD) sb[threadIdx.x] = b[threadIdx.x];
    if (FUSEZ && threadIdx.x < HD * NC) sW4l[threadIdx.x] = W4l[threadIdx.x];
    __syncthreads();
    const uint2* hb2 = (const uint2*)hbin;
    int lane = threadIdx.x & 63, wid = threadIdx.x >> 6;
    int sub = lane >> 4;       // edge slot 0..3
    int fq = lane & 15;        // uint2 index in row (features 4fq..4fq+3)
    int ngroups = (NN + 3) / 4;
    for (int g = blockIdx.x; g < ngroups; g += gridDim.x) {
        int n = g * 4 + wid;
        bool act = n < NN;
        if (act) {
            int s0 = rs[n], d = deg[n];
            uint hu = hbin[(size_t)n * 32 + (lane >> 1)];   // self feature, hoisted
            float hv = (lane & 1) ? bfhi(hu) : bflo(hu);
            float4 A0 = make_float4(0.f, 0.f, 0.f, 0.f);
            float4 A1 = A0, A2 = A0, A3 = A0, A4 = A0, A5 = A0, A6 = A0, A7 = A0;
            for (int base = 0; base < d; base += 64) {
                int rem = d - base; if (rem > 64) rem = 64;
                int idxv = (lane < rem) ? csr[s0 + base + lane] : 0;
                int j = 0;
                for (; j + 32 <= rem; j += 32) {
                    int i0 = __shfl(idxv, j + 0 + sub);
                    int i1 = __shfl(idxv, j + 4 + sub);
                    int i2 = __shfl(idxv, j + 8 + sub);
                    int i3 = __shfl(idxv, j + 12 + sub);
                    int i4 = __shfl(idxv, j + 16 + sub);
                    int i5 = __shfl(idxv, j + 20 + sub);
                    int i6 = __shfl(idxv, j + 24 + sub);
                    int i7 = __shfl(idxv, j + 28 + sub);
                    bfadd4(A0, hb2[(size_t)i0 * 16 + fq]);
                    bfadd4(A1, hb2[(size_t)i1 * 16 + fq]);
                    bfadd4(A2, hb2[(size_t)i2 * 16 + fq]);
                    bfadd4(A3, hb2[(size_t)i3 * 16 + fq]);
                    bfadd4(A4, hb2[(size_t)i4 * 16 + fq]);
                    bfadd4(A5, hb2[(size_t)i5 * 16 + fq]);
                    bfadd4(A6, hb2[(size_t)i6 * 16 + fq]);
                    bfadd4(A7, hb2[(size_t)i7 * 16 + fq]);
                }
                for (; j + 4 <= rem; j += 4) {
                    int i0 = __shfl(idxv, j + sub);
                    bfadd4(A0, hb2[(size_t)i0 * 16 + fq]);
                }
                if (j < rem) {
                    int i0 = __shfl(idxv, j + sub);
                    if (sub < rem - j) bfadd4(A0, hb2[(size_t)i0 * 16 + fq]);
                }
            }
            A0.x += A1.x + A2.x + A3.x + A4.x + A5.x + A6.x + A7.x;
            A0.y += A1.y + A2.y + A3.y + A4.y + A5.y + A6.y + A7.y;
            A0.z += A1.z + A2.z + A3.z + A4.z + A5.z + A6.z + A7.z;
            A0.w += A1.w + A2.w + A3.w + A4.w + A5.w + A6.w + A7.w;
            for (int off = 16; off <= 32; off <<= 1) {
                A0.x += __shfl_xor(A0.x, off);
                A0.y += __shfl_xor(A0.y, off);
                A0.z += __shfl_xor(A0.z, off);
                A0.w += __shfl_xor(A0.w, off);
            }
            float inv = 1.0f / (float)(d > 1 ? d : 1);
            A0.x *= inv; A0.y *= inv; A0.z *= inv; A0.w *= inv;
            float e0 = __shfl(A0.x, lane >> 2);
            float e1 = __shfl(A0.y, lane >> 2);
            float e2 = __shfl(A0.z, lane >> 2);
            float e3 = __shfl(A0.w, lane >> 2);
            int c = lane & 3;
            float sel = (c == 0) ? e0 : (c == 1) ? e1 : (c == 2) ? e2 : e3;
            sAH[wid][lane] = make_float2(sel, hv);
        }
        // no barrier: sAH[wid] is per-wave scratch
        float out = sb[lane];
#pragma unroll 8
        for (int k = 0; k < HD; ++k) {
            uint wu = sWp[k][lane];
            float2 ah = sAH[wid][k];
            out += ah.x * bflo(wu) + ah.y * bfhi(wu);
        }
        out = fmaxf(out, 0.f);
        float o2 = __shfl_xor(out, 1);
        if (act && !(lane & 1)) hbout[(size_t)n * 32 + (lane >> 1)] = pack2bf16(out, o2);
        if (FUSEZ) {
            float r0 = out * sW4l[lane * NC + 0];
            float r1 = out * sW4l[lane * NC + 1];
            for (int off = 32; off; off >>= 1) {
                r0 += __shfl_xor(r0, off);
                r1 += __shfl_xor(r1, off);
            }
            if (act && lane == 0) ((float2*)z)[n] = make_float2(r0, r1);
        }
    }
}

// ---------------- Layer 4 + graph pooling sum ----------------

__global__ __launch_bounds__(256) void k_pool(
    const uint* __restrict__ h3, const float* __restrict__ z,
    const float* __restrict__ W4r, const float* __restrict__ b4,
    const int* __restrict__ rs, const int* __restrict__ deg, const int* __restrict__ csr,
    const int* __restrict__ batch, float* __restrict__ gsum) {
    __shared__ float sW[HD * NC];
    if (threadIdx.x < HD * NC) sW[threadIdx.x] = W4r[threadIdx.x];
    __syncthreads();
    const float2* z2 = (const float2*)z;
    int lane = threadIdx.x & 63, wid = threadIdx.x >> 6;
    int stride = gridDim.x * 4;
    for (int n = blockIdx.x * 4 + wid; n < NN; n += stride) {
        float r0 = 0.f, r1 = 0.f;
        if (lane < 32) {
            uint u = h3[(size_t)n * 32 + lane];
            float f0 = bflo(u), f1 = bfhi(u);
            r0 = f0 * sW[(2 * lane) * NC + 0] + f1 * sW[(2 * lane + 1) * NC + 0];
            r1 = f0 * sW[(2 * lane) * NC + 1] + f1 * sW[(2 * lane + 1) * NC + 1];
        }
        int s0 = rs[n], d = deg[n];
        float a0 = 0.f, a1 = 0.f;
        for (int j = lane; j < d; j += 64) {
            int s = csr[s0 + j];
            float2 zv = z2[s];
            a0 += zv.x;
            a1 += zv.y;
        }
        for (int off = 32; off; off >>= 1) {
            r0 += __shfl_xor(r0, off);
            r1 += __shfl_xor(r1, off);
            a0 += __shfl_xor(a0, off);
            a1 += __shfl_xor(a1, off);
        }
        if (lane == 0) {
            float inv = 1.0f / (float)(d > 1 ? d : 1);
            float o0 = a0 * inv + r0 + b4[0];
            float o1 = a1 * inv + r1 + b4[1];
            int gg = batch[n];
            atomicAdd(&gsum[gg * 2 + 0], o0);
            atomicAdd(&gsum[gg * 2 + 1], o1);
        }
    }
}

__global__ void k_final(const float* __restrict__ gsum, const int* __restrict__ gstart,
                        const int* __restrict__ gend, float* __restrict__ out) {
    int g = blockIdx.x * blockDim.x + threadIdx.x;
    if (g < NG) {
        int cnt = gend[g] - gstart[g];
        float inv = 1.0f / (float)(cnt > 1 ? cnt : 1);
        float p0 = gsum[g * 2 + 0] * inv;
        float p1 = gsum[g * 2 + 1] * inv;
        float m = fmaxf(p0, p1);
        float lse = m + logf(expf(p0 - m) + expf(p1 - m));
        out[g * 2 + 0] = p0 - lse;
        out[g * 2 + 1] = p1 - lse;
    }
}

// ---------------- launch ----------------

extern "C" void kernel_launch(void* const* d_in, const int* in_sizes, int n_in,
                              void* d_out, int out_size, void* d_ws, size_t ws_size,
                              hipStream_t stream) {
    const float* x   = (const float*)d_in[0];
    const float* W1l = (const float*)d_in[1];
    const float* W1r = (const float*)d_in[2];
    const float* b1  = (const float*)d_in[3];
    const float* W2l = (const float*)d_in[4];
    const float* W2r = (const float*)d_in[5];
    const float* b2  = (const float*)d_in[6];
    const float* W3l = (const float*)d_in[7];
    const float* W3r = (const float*)d_in[8];
    const float* b3  = (const float*)d_in[9];
    const float* W4l = (const float*)d_in[10];
    const float* W4r = (const float*)d_in[11];
    const float* b4  = (const float*)d_in[12];
    const int* ei    = (const int*)d_in[13];
    const int* batch = (const int*)d_in[14];
    const int* src = ei;
    const int* dst = ei + NE;
    float* out = (float*)d_out;

    char* w = (char*)d_ws;
    int* deg    = (int*)w; w += (size_t)NN * 4;
    int* rs     = (int*)w; w += (size_t)NN * 4;
    int* csr    = (int*)w; w += (size_t)NE * 4;
    int* gstart = (int*)w; w += (size_t)NG * 4;
    int* gend   = (int*)w; w += (size_t)NG * 4;
    int* bkcnt  = (int*)w; w += NBUK * 4;
    int* bbase  = (int*)w; w += (NBUK + 1) * 4;
    int* bcur   = (int*)w; w += NBUK * 4;
    w = (char*)(((uintptr_t)w + 255) & ~(uintptr_t)255);
    uint* xb    = (uint*)w; w += (size_t)NN * 8 * 4;
    uint* hbA   = (uint*)w; w += (size_t)NN * 32 * 4;
    uint* hbB   = (uint*)w; w += (size_t)NN * 32 * 4;
    float* z    = (float*)w; w += (size_t)NN * NC * 4;
    float* gsum = (float*)w; w += (size_t)NG * NC * 4;
    int* pairs = (int*)hbB;  // alias: NE*4 == NN*32*4 bytes; dead before layer 2 writes hbB

    const int P1B = (NE + P1E - 1) / P1E;  // 782

    hipMemsetAsync(bkcnt, 0, NBUK * 4, stream);
    hipMemsetAsync(gstart, 0, (size_t)NG * 4, stream);
    hipMemsetAsync(gend, 0, (size_t)NG * 4, stream);
    hipMemsetAsync(gsum, 0, (size_t)NG * NC * 4, stream);

    k_hist_bucket<<<P1B, 256, 0, stream>>>(dst, bkcnt);
    k_packx<<<(NN * 8 + 255) / 256, 256, 0, stream>>>(x, xb);
    k_gbounds<<<(NN + 255) / 256, 256, 0, stream>>>(batch, gstart, gend);
    k_scanb<<<1, NBUK, 0, stream>>>(bkcnt, bbase, bcur);
    k_pass1<<<P1B, 256, 0, stream>>>(src, dst, bcur, pairs);
    k_pass2<<<NBUK, 256, 0, stream>>>(pairs, bbase, deg, rs, csr);

    k_layer1<<<1536, 256, 0, stream>>>(x, xb, hbA, W1l, W1r, b1, rs, deg, csr);
    k_layerH<false><<<1536, 256, 0, stream>>>(hbA, hbB, W2l, W2r, b2, nullptr, nullptr, rs, deg, csr);
    k_layerH<true><<<1536, 256, 0, stream>>>(hbB, hbA, W3l, W3r, b3, W4l, z, rs, deg, csr);
    k_pool<<<2048, 256, 0, stream>>>(hbA, z, W4r, b4, rs, deg, csr, batch, gsum);
    k_final<<<(NG + 255) / 256, 256, 0, stream>>>(gsum, gstart, gend, out);
}